// Round 1
// baseline (2409.834 us; speedup 1.0000x reference)
//
#include <hip/hip_runtime.h>

#define N_NODES 50000
#define N_EDGES 800000
#define EP_EDGES (N_EDGES + N_NODES)
#define N_GRAPHS 256

// ---------- float <-> ordered-uint for atomicMax on floats ----------
__device__ __forceinline__ unsigned fenc(float x) {
  unsigned b = __float_as_uint(x);
  return (b & 0x80000000u) ? ~b : (b | 0x80000000u);
}
__device__ __forceinline__ float fdec(unsigned u) {
  return (u & 0x80000000u) ? __uint_as_float(u & 0x7fffffffu)
                           : __uint_as_float(~u);
}

// ---------- tiled f32 GEMM: C[M,N] = A[M,K] * W[N,K]^T ----------
// 64x64 tile, TK=16, 256 threads, 4x4 microtile.
__global__ __launch_bounds__(256) void gemm_nt(
    const float* __restrict__ A, const float* __restrict__ W,
    float* __restrict__ C, int M, int Nout, int K) {
  __shared__ float As[16][68];  // [k][m], stride 68 to soften bank conflicts
  __shared__ float Bs[16][68];  // [k][n]
  const int t = threadIdx.x;
  const int tx = t & 15, ty = t >> 4;
  const int m0 = blockIdx.y * 64;
  const int n0 = blockIdx.x * 64;
  const int lcol = t & 15;   // k within tile
  const int lrow = t >> 4;   // row base

  float acc[4][4] = {};
  for (int k0 = 0; k0 < K; k0 += 16) {
#pragma unroll
    for (int r = 0; r < 4; ++r) {
      int m = m0 + lrow + 16 * r;
      As[lcol][lrow + 16 * r] = (m < M) ? A[m * K + k0 + lcol] : 0.f;
      int n = n0 + lrow + 16 * r;  // Nout is a multiple of 64 -> always in range
      Bs[lcol][lrow + 16 * r] = W[n * K + k0 + lcol];
    }
    __syncthreads();
#pragma unroll
    for (int k = 0; k < 16; ++k) {
      float a[4], b[4];
      *(float4*)a = *(const float4*)&As[k][ty * 4];
      *(float4*)b = *(const float4*)&Bs[k][tx * 4];
#pragma unroll
      for (int i = 0; i < 4; ++i)
#pragma unroll
        for (int j = 0; j < 4; ++j) acc[i][j] += a[i] * b[j];
    }
    __syncthreads();
  }
#pragma unroll
  for (int i = 0; i < 4; ++i) {
    int m = m0 + ty * 4 + i;
    if (m < M) {
      float4 v = make_float4(acc[i][0], acc[i][1], acc[i][2], acc[i][3]);
      *(float4*)&C[m * Nout + n0 + tx * 4] = v;
    }
  }
}

// ---------- per-node attention scores: alo/ahi [N,H] ----------
// blockDim = HC (256 or 64); each 64-lane wave reduces one head.
__global__ void attn_scores(const float* __restrict__ h,
                            const float* __restrict__ a_src,
                            const float* __restrict__ a_dst,
                            float* __restrict__ alo, float* __restrict__ ahi,
                            int HC, int H) {
  const int n = blockIdx.x;
  const int t = threadIdx.x;
  float v = h[n * HC + t];
  float s = v * a_src[t];
  float d = v * a_dst[t];
#pragma unroll
  for (int off = 32; off; off >>= 1) {
    s += __shfl_down(s, off, 64);
    d += __shfl_down(d, off, 64);
  }
  if ((t & 63) == 0) {
    int hd = t >> 6;
    alo[n * H + hd] = s;
    ahi[n * H + hd] = d;
  }
}

// ---------- edge pass 1: e = lrelu(alo[src]+ahi[dst]); segment max ----------
template <int H>
__global__ void edge_pass1(const int* __restrict__ ei,
                           const float* __restrict__ alo,
                           const float* __restrict__ ahi,
                           float* __restrict__ ebuf,
                           unsigned* __restrict__ mkey, int total) {
  int idx = blockIdx.x * 256 + threadIdx.x;
  if (idx >= total) return;
  int e = idx / H, hd = idx % H;
  int s, d;
  if (e < N_EDGES) { s = ei[e]; d = ei[N_EDGES + e]; }
  else             { s = d = e - N_EDGES; }
  float v = alo[s * H + hd] + ahi[d * H + hd];
  v = v > 0.f ? v : 0.2f * v;  // leaky_relu, neg_slope 0.2
  ebuf[idx] = v;
  atomicMax(&mkey[d * H + hd], fenc(v));
}

// ---------- edge pass 2: ex = exp(e - m[dst]); segment sum ----------
template <int H>
__global__ void edge_pass2(const int* __restrict__ ei,
                           float* __restrict__ ebuf,
                           const unsigned* __restrict__ mkey,
                           float* __restrict__ den, int total) {
  int idx = blockIdx.x * 256 + threadIdx.x;
  if (idx >= total) return;
  int e = idx / H, hd = idx % H;
  int d;
  if (e < N_EDGES) d = ei[N_EDGES + e];
  else             d = e - N_EDGES;
  float m = fdec(mkey[d * H + hd]);
  float ex = expf(ebuf[idx] - m);
  ebuf[idx] = ex;
  atomicAdd(&den[d * H + hd], ex);
}

// ---------- edge pass 3: acc[dst] += h[src] * alpha ----------
// one block per edge, blockDim = H*64
template <int H>
__global__ void edge_pass3(const int* __restrict__ ei,
                           const float* __restrict__ h,
                           const float* __restrict__ ex,
                           const float* __restrict__ den,
                           float* __restrict__ acc) {
  const int e = blockIdx.x;
  const int t = threadIdx.x;
  const int hd = t >> 6;
  int s, d;
  if (e < N_EDGES) { s = ei[e]; d = ei[N_EDGES + e]; }
  else             { s = d = e - N_EDGES; }
  float alpha = ex[e * H + hd] / (den[d * H + hd] + 1e-16f);
  atomicAdd(&acc[d * (H * 64) + t], h[s * (H * 64) + t] * alpha);
}

// ---------- epilogue: feat = elu(acc + bias) in place ----------
__global__ void epilogue(float* __restrict__ acc, const float* __restrict__ b,
                         int total, int hcMask) {
  int i = blockIdx.x * 256 + threadIdx.x;
  if (i >= total) return;
  float v = acc[i] + b[i & hcMask];
  acc[i] = v > 0.f ? v : (expf(v) - 1.f);
}

// ---------- global mean pool (accumulate) ----------
__global__ void pool_acc(const float* __restrict__ feat,
                         const int* __restrict__ batch,
                         float* __restrict__ gsum, float* __restrict__ gcnt) {
  const int n = blockIdx.x;
  const int t = threadIdx.x;
  int b = batch[n];
  atomicAdd(&gsum[b * 64 + t], feat[n * 64 + t]);
  if (t == 0) atomicAdd(&gcnt[b], 1.f);
}

// ---------- fused MLP heads: 256 blocks x 64 threads ----------
__global__ void heads(const float* __restrict__ gsum,
                      const float* __restrict__ gcnt,
                      const float* __restrict__ Wc1, const float* __restrict__ bc1,
                      const float* __restrict__ Wc2, const float* __restrict__ bc2,
                      const float* __restrict__ Wr1, const float* __restrict__ br1,
                      const float* __restrict__ Wr2, const float* __restrict__ br2,
                      float* __restrict__ out) {
  __shared__ float g[64];
  const int gi = blockIdx.x, j = threadIdx.x;
  float cnt = gcnt[gi];
  cnt = cnt < 1.f ? 1.f : cnt;
  g[j] = gsum[gi * 64 + j] / cnt;
  __syncthreads();
  float hc = bc1[j], hr = br1[j];
#pragma unroll 8
  for (int c = 0; c < 64; ++c) {
    float gv = g[c];
    hc += gv * Wc1[j * 64 + c];
    hr += gv * Wr1[j * 64 + c];
  }
  hc = fmaxf(hc, 0.f) * Wc2[j];
  hr = fmaxf(hr, 0.f) * Wr2[j];
#pragma unroll
  for (int off = 32; off; off >>= 1) {
    hc += __shfl_down(hc, off, 64);
    hr += __shfl_down(hr, off, 64);
  }
  if (j == 0) {
    out[gi] = hc + bc2[0];
    out[N_GRAPHS + gi] = hr + br2[0];
  }
}

// ---------- host-side per-layer driver ----------
static void run_layer(const float* fin, int K, int H, const float* W,
                      const float* a_s, const float* a_d, const float* bias,
                      float* h_buf, float* feat, float* e_buf, float* alo,
                      float* ahi, unsigned* mkey, float* den, const int* ei,
                      hipStream_t stream) {
  const int HC = H * 64;
  dim3 ggrid(HC / 64, (N_NODES + 63) / 64);
  gemm_nt<<<ggrid, 256, 0, stream>>>(fin, W, h_buf, N_NODES, HC, K);
  // feat may alias fin: memset is stream-ordered after the GEMM finished reading it
  hipMemsetAsync(feat, 0, (size_t)N_NODES * HC * 4, stream);
  hipMemsetAsync(mkey, 0, (size_t)N_NODES * H * 4, stream);
  hipMemsetAsync(den, 0, (size_t)N_NODES * H * 4, stream);
  attn_scores<<<N_NODES, HC, 0, stream>>>(h_buf, a_s, a_d, alo, ahi, HC, H);
  const int total = EP_EDGES * H;
  const int blk = (total + 255) / 256;
  if (H == 4) {
    edge_pass1<4><<<blk, 256, 0, stream>>>(ei, alo, ahi, e_buf, mkey, total);
    edge_pass2<4><<<blk, 256, 0, stream>>>(ei, e_buf, mkey, den, total);
    edge_pass3<4><<<EP_EDGES, 256, 0, stream>>>(ei, h_buf, e_buf, den, feat);
  } else {
    edge_pass1<1><<<blk, 256, 0, stream>>>(ei, alo, ahi, e_buf, mkey, total);
    edge_pass2<1><<<blk, 256, 0, stream>>>(ei, e_buf, mkey, den, total);
    edge_pass3<1><<<EP_EDGES, 64, 0, stream>>>(ei, h_buf, e_buf, den, feat);
  }
  const int tot2 = N_NODES * HC;
  epilogue<<<(tot2 + 255) / 256, 256, 0, stream>>>(feat, bias, tot2, HC - 1);
}

extern "C" void kernel_launch(void* const* d_in, const int* in_sizes, int n_in,
                              void* d_out, int out_size, void* d_ws,
                              size_t ws_size, hipStream_t stream) {
  const float* x   = (const float*)d_in[0];
  const int* ei    = (const int*)d_in[1];
  const int* batch = (const int*)d_in[2];
  const float* W1  = (const float*)d_in[3];
  const float* as1 = (const float*)d_in[4];
  const float* ad1 = (const float*)d_in[5];
  const float* b1  = (const float*)d_in[6];
  const float* W2  = (const float*)d_in[7];
  const float* as2 = (const float*)d_in[8];
  const float* ad2 = (const float*)d_in[9];
  const float* b2  = (const float*)d_in[10];
  const float* W3  = (const float*)d_in[11];
  const float* as3 = (const float*)d_in[12];
  const float* ad3 = (const float*)d_in[13];
  const float* b3  = (const float*)d_in[14];
  const float* Wc1 = (const float*)d_in[15];
  const float* bc1 = (const float*)d_in[16];
  const float* Wc2 = (const float*)d_in[17];
  const float* bc2 = (const float*)d_in[18];
  const float* Wr1 = (const float*)d_in[19];
  const float* br1 = (const float*)d_in[20];
  const float* Wr2 = (const float*)d_in[21];
  const float* br2 = (const float*)d_in[22];
  float* out = (float*)d_out;

  // workspace layout (floats)
  float* ws = (float*)d_ws;
  float* h_buf = ws;                                   // N*256
  float* feat  = h_buf + (size_t)N_NODES * 256;        // N*256 (layer io + acc)
  float* e_buf = feat + (size_t)N_NODES * 256;         // EP*4
  float* alo   = e_buf + (size_t)EP_EDGES * 4;         // N*4
  float* ahi   = alo + (size_t)N_NODES * 4;            // N*4
  unsigned* mkey = (unsigned*)(ahi + (size_t)N_NODES * 4);  // N*4
  float* den   = (float*)mkey + (size_t)N_NODES * 4;   // N*4
  float* gsum  = den + (size_t)N_NODES * 4;            // 256*64
  float* gcnt  = gsum + (size_t)N_GRAPHS * 64;         // 256

  // layer 1: x[N,128] -> feat[N,256]
  run_layer(x, 128, 4, W1, as1, ad1, b1, h_buf, feat, e_buf, alo, ahi, mkey,
            den, ei, stream);
  // layer 2: feat[N,256] -> feat[N,256]
  run_layer(feat, 256, 4, W2, as2, ad2, b2, h_buf, feat, e_buf, alo, ahi, mkey,
            den, ei, stream);
  // layer 3: feat[N,256] -> feat[N,64]
  run_layer(feat, 256, 1, W3, as3, ad3, b3, h_buf, feat, e_buf, alo, ahi, mkey,
            den, ei, stream);

  // global mean pool + heads
  hipMemsetAsync(gsum, 0, (size_t)N_GRAPHS * 64 * 4, stream);
  hipMemsetAsync(gcnt, 0, (size_t)N_GRAPHS * 4, stream);
  pool_acc<<<N_NODES, 64, 0, stream>>>(feat, batch, gsum, gcnt);
  heads<<<N_GRAPHS, 64, 0, stream>>>(gsum, gcnt, Wc1, bc1, Wc2, bc2, Wr1, br1,
                                     Wr2, br2, out);
}

// Round 2
// 1124.063 us; speedup vs baseline: 2.1439x; 2.1439x over previous
//
#include <hip/hip_runtime.h>

#define N_NODES 50000
#define N_EDGES 800000
#define EP_EDGES (N_EDGES + N_NODES)
#define N_GRAPHS 256
#define NBLK_SCAN ((N_NODES + 255) / 256)

// ---------- tiled f32 GEMM: C[M,N] = A[M,K] * W[N,K]^T ----------
__global__ __launch_bounds__(256) void gemm_nt(
    const float* __restrict__ A, const float* __restrict__ W,
    float* __restrict__ C, int M, int Nout, int K) {
  __shared__ float As[16][68];
  __shared__ float Bs[16][68];
  const int t = threadIdx.x;
  const int tx = t & 15, ty = t >> 4;
  const int m0 = blockIdx.y * 64;
  const int n0 = blockIdx.x * 64;
  const int lcol = t & 15;
  const int lrow = t >> 4;

  float acc[4][4] = {};
  for (int k0 = 0; k0 < K; k0 += 16) {
#pragma unroll
    for (int r = 0; r < 4; ++r) {
      int m = m0 + lrow + 16 * r;
      As[lcol][lrow + 16 * r] = (m < M) ? A[m * K + k0 + lcol] : 0.f;
      int n = n0 + lrow + 16 * r;
      Bs[lcol][lrow + 16 * r] = W[n * K + k0 + lcol];
    }
    __syncthreads();
#pragma unroll
    for (int k = 0; k < 16; ++k) {
      float a[4], b[4];
      *(float4*)a = *(const float4*)&As[k][ty * 4];
      *(float4*)b = *(const float4*)&Bs[k][tx * 4];
#pragma unroll
      for (int i = 0; i < 4; ++i)
#pragma unroll
        for (int j = 0; j < 4; ++j) acc[i][j] += a[i] * b[j];
    }
    __syncthreads();
  }
#pragma unroll
  for (int i = 0; i < 4; ++i) {
    int m = m0 + ty * 4 + i;
    if (m < M) {
      float4 v = make_float4(acc[i][0], acc[i][1], acc[i][2], acc[i][3]);
      *(float4*)&C[m * Nout + n0 + tx * 4] = v;
    }
  }
}

// ---------- CSR build ----------
__global__ void k_hist(const int* __restrict__ ei, int* __restrict__ deg) {
  int e = blockIdx.x * 256 + threadIdx.x;
  if (e >= EP_EDGES) return;
  int d = (e < N_EDGES) ? ei[N_EDGES + e] : e - N_EDGES;
  atomicAdd(&deg[d], 1);
}

__global__ void k_scan_local(const int* __restrict__ deg,
                             int* __restrict__ rowstart,
                             int* __restrict__ bsum) {
  __shared__ int sh[256];
  const int tid = threadIdx.x;
  const int i = blockIdx.x * 256 + tid;
  int v = (i < N_NODES) ? deg[i] : 0;
  sh[tid] = v;
  __syncthreads();
  for (int off = 1; off < 256; off <<= 1) {
    int add = (tid >= off) ? sh[tid - off] : 0;
    __syncthreads();
    sh[tid] += add;
    __syncthreads();
  }
  if (i < N_NODES) rowstart[i] = sh[tid] - v;  // exclusive
  if (tid == 255) bsum[blockIdx.x] = sh[255];
}

__global__ void k_scan_bsum(int* __restrict__ bsum, int* __restrict__ boff) {
  __shared__ int sh[256];
  const int tid = threadIdx.x;
  int v = (tid < NBLK_SCAN) ? bsum[tid] : 0;
  sh[tid] = v;
  __syncthreads();
  for (int off = 1; off < 256; off <<= 1) {
    int add = (tid >= off) ? sh[tid - off] : 0;
    __syncthreads();
    sh[tid] += add;
    __syncthreads();
  }
  boff[tid] = sh[tid] - v;  // exclusive
}

__global__ void k_scan_add(int* __restrict__ rowstart,
                           const int* __restrict__ boff) {
  int i = blockIdx.x * 256 + threadIdx.x;
  if (i < N_NODES) rowstart[i] += boff[i >> 8];
  if (i == N_NODES) rowstart[N_NODES] = EP_EDGES;
}

__global__ void k_scatter(const int* __restrict__ ei,
                          const int* __restrict__ rowstart,
                          int* __restrict__ fill, int* __restrict__ esrc) {
  int e = blockIdx.x * 256 + threadIdx.x;
  if (e >= EP_EDGES) return;
  int s, d;
  if (e < N_EDGES) { s = ei[e]; d = ei[N_EDGES + e]; }
  else             { s = d = e - N_EDGES; }
  int pos = rowstart[d] + atomicAdd(&fill[d], 1);
  esrc[pos] = s;
}

// ---------- per-node attention scores: alo/ahi [N,H] ----------
__global__ void attn_scores(const float* __restrict__ h,
                            const float* __restrict__ a_src,
                            const float* __restrict__ a_dst,
                            float* __restrict__ alo, float* __restrict__ ahi,
                            int HC, int H) {
  const int n = blockIdx.x;
  const int t = threadIdx.x;
  float v = h[n * HC + t];
  float s = v * a_src[t];
  float d = v * a_dst[t];
#pragma unroll
  for (int off = 32; off; off >>= 1) {
    s += __shfl_down(s, off, 64);
    d += __shfl_down(d, off, 64);
  }
  if ((t & 63) == 0) {
    int hd = t >> 6;
    alo[n * H + hd] = s;
    ahi[n * H + hd] = d;
  }
}

// ---------- fused segment softmax -> alpha (one wave per dst) ----------
template <int H>
__global__ __launch_bounds__(64) void attn_alpha(
    const int* __restrict__ rowstart, const int* __restrict__ esrc,
    const float* __restrict__ alo, const float* __restrict__ ahi,
    float* __restrict__ abuf) {
  const int d = blockIdx.x;
  const int lane = threadIdx.x;
  const int s0 = rowstart[d], s1 = rowstart[d + 1];
  float ah[H];
#pragma unroll
  for (int h = 0; h < H; ++h) ah[h] = ahi[d * H + h];
  float mx[H];
#pragma unroll
  for (int h = 0; h < H; ++h) mx[h] = -1e30f;
  for (int i = s0 + lane; i < s1; i += 64) {
    int s = esrc[i];
#pragma unroll
    for (int h = 0; h < H; ++h) {
      float v = alo[s * H + h] + ah[h];
      v = v > 0.f ? v : 0.2f * v;
      mx[h] = fmaxf(mx[h], v);
    }
  }
#pragma unroll
  for (int off = 32; off; off >>= 1)
#pragma unroll
    for (int h = 0; h < H; ++h) mx[h] = fmaxf(mx[h], __shfl_xor(mx[h], off, 64));
  float sm[H] = {};
  for (int i = s0 + lane; i < s1; i += 64) {
    int s = esrc[i];
#pragma unroll
    for (int h = 0; h < H; ++h) {
      float v = alo[s * H + h] + ah[h];
      v = v > 0.f ? v : 0.2f * v;
      sm[h] += __expf(v - mx[h]);
    }
  }
#pragma unroll
  for (int off = 32; off; off >>= 1)
#pragma unroll
    for (int h = 0; h < H; ++h) sm[h] += __shfl_xor(sm[h], off, 64);
  float inv[H];
#pragma unroll
  for (int h = 0; h < H; ++h) inv[h] = 1.f / (sm[h] + 1e-16f);
  for (int i = s0 + lane; i < s1; i += 64) {
    int s = esrc[i];
#pragma unroll
    for (int h = 0; h < H; ++h) {
      float v = alo[s * H + h] + ah[h];
      v = v > 0.f ? v : 0.2f * v;
      abuf[i * H + h] = __expf(v - mx[h]) * inv[h];
    }
  }
}

// ---------- aggregation: one block per dst, wave per head; bias+ELU fused ----
template <int H>
__global__ __launch_bounds__(H * 64) void aggregate(
    const int* __restrict__ rowstart, const int* __restrict__ esrc,
    const float* __restrict__ hbuf, const float* __restrict__ abuf,
    const float* __restrict__ bias, float* __restrict__ feat) {
  const int d = blockIdx.x;
  const int t = threadIdx.x;
  const int h = t >> 6;
  const int s0 = rowstart[d], s1 = rowstart[d + 1];
  float acc = 0.f;
  for (int i = s0; i < s1; ++i) {
    int s = esrc[i];
    float a = abuf[i * H + h];
    acc += a * hbuf[s * (H * 64) + t];
  }
  float v = acc + bias[t];
  feat[d * (H * 64) + t] = v > 0.f ? v : __expf(v) - 1.f;
}

// ---------- global mean pool (accumulate) ----------
__global__ void pool_acc(const float* __restrict__ feat,
                         const int* __restrict__ batch,
                         float* __restrict__ gsum, float* __restrict__ gcnt) {
  const int n = blockIdx.x;
  const int t = threadIdx.x;
  int b = batch[n];
  atomicAdd(&gsum[b * 64 + t], feat[n * 64 + t]);
  if (t == 0) atomicAdd(&gcnt[b], 1.f);
}

// ---------- fused MLP heads ----------
__global__ void heads(const float* __restrict__ gsum,
                      const float* __restrict__ gcnt,
                      const float* __restrict__ Wc1, const float* __restrict__ bc1,
                      const float* __restrict__ Wc2, const float* __restrict__ bc2,
                      const float* __restrict__ Wr1, const float* __restrict__ br1,
                      const float* __restrict__ Wr2, const float* __restrict__ br2,
                      float* __restrict__ out) {
  __shared__ float g[64];
  const int gi = blockIdx.x, j = threadIdx.x;
  float cnt = gcnt[gi];
  cnt = cnt < 1.f ? 1.f : cnt;
  g[j] = gsum[gi * 64 + j] / cnt;
  __syncthreads();
  float hc = bc1[j], hr = br1[j];
#pragma unroll 8
  for (int c = 0; c < 64; ++c) {
    float gv = g[c];
    hc += gv * Wc1[j * 64 + c];
    hr += gv * Wr1[j * 64 + c];
  }
  hc = fmaxf(hc, 0.f) * Wc2[j];
  hr = fmaxf(hr, 0.f) * Wr2[j];
#pragma unroll
  for (int off = 32; off; off >>= 1) {
    hc += __shfl_down(hc, off, 64);
    hr += __shfl_down(hr, off, 64);
  }
  if (j == 0) {
    out[gi] = hc + bc2[0];
    out[N_GRAPHS + gi] = hr + br2[0];
  }
}

// ---------- per-layer driver ----------
static void run_layer(const float* fin, int K, int H, const float* W,
                      const float* a_s, const float* a_d, const float* bias,
                      float* h_buf, float* feat, float* abuf, float* alo,
                      float* ahi, const int* rowstart, const int* esrc,
                      hipStream_t stream) {
  const int HC = H * 64;
  dim3 ggrid(HC / 64, (N_NODES + 63) / 64);
  gemm_nt<<<ggrid, 256, 0, stream>>>(fin, W, h_buf, N_NODES, HC, K);
  attn_scores<<<N_NODES, HC, 0, stream>>>(h_buf, a_s, a_d, alo, ahi, HC, H);
  if (H == 4) {
    attn_alpha<4><<<N_NODES, 64, 0, stream>>>(rowstart, esrc, alo, ahi, abuf);
    aggregate<4><<<N_NODES, 256, 0, stream>>>(rowstart, esrc, h_buf, abuf,
                                              bias, feat);
  } else {
    attn_alpha<1><<<N_NODES, 64, 0, stream>>>(rowstart, esrc, alo, ahi, abuf);
    aggregate<1><<<N_NODES, 64, 0, stream>>>(rowstart, esrc, h_buf, abuf,
                                             bias, feat);
  }
}

extern "C" void kernel_launch(void* const* d_in, const int* in_sizes, int n_in,
                              void* d_out, int out_size, void* d_ws,
                              size_t ws_size, hipStream_t stream) {
  const float* x   = (const float*)d_in[0];
  const int* ei    = (const int*)d_in[1];
  const int* batch = (const int*)d_in[2];
  const float* W1  = (const float*)d_in[3];
  const float* as1 = (const float*)d_in[4];
  const float* ad1 = (const float*)d_in[5];
  const float* b1  = (const float*)d_in[6];
  const float* W2  = (const float*)d_in[7];
  const float* as2 = (const float*)d_in[8];
  const float* ad2 = (const float*)d_in[9];
  const float* b2  = (const float*)d_in[10];
  const float* W3  = (const float*)d_in[11];
  const float* as3 = (const float*)d_in[12];
  const float* ad3 = (const float*)d_in[13];
  const float* b3  = (const float*)d_in[14];
  const float* Wc1 = (const float*)d_in[15];
  const float* bc1 = (const float*)d_in[16];
  const float* Wc2 = (const float*)d_in[17];
  const float* bc2 = (const float*)d_in[18];
  const float* Wr1 = (const float*)d_in[19];
  const float* br1 = (const float*)d_in[20];
  const float* Wr2 = (const float*)d_in[21];
  const float* br2 = (const float*)d_in[22];
  float* out = (float*)d_out;

  // workspace layout (4-byte units)
  float* ws = (float*)d_ws;
  float* h_buf = ws;                                   // N*256
  float* feat  = h_buf + (size_t)N_NODES * 256;        // N*256
  float* abuf  = feat + (size_t)N_NODES * 256;         // EP*4
  float* alo   = abuf + (size_t)EP_EDGES * 4;          // N*4
  float* ahi   = alo + (size_t)N_NODES * 4;            // N*4
  int* rowstart = (int*)(ahi + (size_t)N_NODES * 4);   // N+2 (pad)
  int* esrc    = rowstart + (N_NODES + 2);             // EP
  float* gsum  = (float*)(esrc + EP_EDGES);            // 256*64
  float* gcnt  = gsum + (size_t)N_GRAPHS * 64;         // 256
  // build-time aliases (only live before the layers / after gsum memset)
  int* deg  = (int*)alo;   // N ints fit in N*4 floats
  int* fill = (int*)ahi;   // N ints
  int* bsum = (int*)gsum;        // 256
  int* boff = (int*)gsum + 256;  // 256

  // ---- CSR build (same work every call) ----
  hipMemsetAsync(deg, 0, (size_t)N_NODES * 4, stream);
  hipMemsetAsync(fill, 0, (size_t)N_NODES * 4, stream);
  const int eblk = (EP_EDGES + 255) / 256;
  k_hist<<<eblk, 256, 0, stream>>>(ei, deg);
  k_scan_local<<<NBLK_SCAN, 256, 0, stream>>>(deg, rowstart, bsum);
  k_scan_bsum<<<1, 256, 0, stream>>>(bsum, boff);
  k_scan_add<<<(N_NODES + 256) / 256, 256, 0, stream>>>(rowstart, boff);
  k_scatter<<<eblk, 256, 0, stream>>>(ei, rowstart, fill, esrc);

  // ---- layers ----
  run_layer(x, 128, 4, W1, as1, ad1, b1, h_buf, feat, abuf, alo, ahi,
            rowstart, esrc, stream);
  run_layer(feat, 256, 4, W2, as2, ad2, b2, h_buf, feat, abuf, alo, ahi,
            rowstart, esrc, stream);
  run_layer(feat, 256, 1, W3, as3, ad3, b3, h_buf, feat, abuf, alo, ahi,
            rowstart, esrc, stream);

  // ---- global mean pool + heads ----
  hipMemsetAsync(gsum, 0, (size_t)N_GRAPHS * 64 * 4, stream);
  hipMemsetAsync(gcnt, 0, (size_t)N_GRAPHS * 4, stream);
  pool_acc<<<N_NODES, 64, 0, stream>>>(feat, batch, gsum, gcnt);
  heads<<<N_GRAPHS, 64, 0, stream>>>(gsum, gcnt, Wc1, bc1, Wc2, bc2, Wr1, br1,
                                     Wr2, br2, out);
}

// Round 3
// 803.998 us; speedup vs baseline: 2.9973x; 1.3981x over previous
//
#include <hip/hip_runtime.h>

#define N_NODES 50000
#define N_EDGES 800000
#define EP_EDGES (N_EDGES + N_NODES)
#define N_GRAPHS 256
#define NBLK_SCAN ((N_NODES + 255) / 256)

typedef unsigned short u16;
typedef __attribute__((ext_vector_type(8))) short s8v;    // 8 x bf16 (4 VGPRs)
typedef __attribute__((ext_vector_type(4))) float f4v;    // mfma accumulator

// ---------- bf16 helpers (RNE) ----------
__device__ __forceinline__ u16 fb(float f) {
  unsigned u = __float_as_uint(f);
  return (u16)((u + 0x7fffu + ((u >> 16) & 1u)) >> 16);
}
__device__ __forceinline__ float bff(u16 s) {
  return __uint_as_float(((unsigned)s) << 16);
}

__global__ void f2b(const float* __restrict__ in, u16* __restrict__ o, int n) {
  int i = blockIdx.x * 256 + threadIdx.x;
  if (i < n) o[i] = fb(in[i]);
}

// ---------- bf16 MFMA GEMM: C[M,Nout](bf16) = A[M,K](bf16) * W[Nout,K](bf16)^T
// 64x64 tile, 4 waves, each wave 32x32 via 2x2 of 16x16x32 mfma.
__global__ __launch_bounds__(256) void gemm_bf16(
    const u16* __restrict__ A, const u16* __restrict__ W,
    u16* __restrict__ C, int M, int Nout, int K) {
  __shared__ u16 As[64][40];  // row stride 80B: 16B-aligned, 2-way-bank free
  __shared__ u16 Bs[64][40];
  const int t = threadIdx.x;
  const int m0 = blockIdx.y * 64, n0 = blockIdx.x * 64;
  const int r = t >> 2, c = t & 3;          // staging: row, 8-elem chunk
  const int w = t >> 6, lane = t & 63;
  const int mi = (w & 1) * 32, ni = (w >> 1) * 32;
  const int quad = lane >> 4, fr = lane & 15;

  f4v c00{}, c01{}, c10{}, c11{};
  for (int k0 = 0; k0 < K; k0 += 32) {
    uint4 av = make_uint4(0, 0, 0, 0);
    int m = m0 + r;
    if (m < M) av = *(const uint4*)&A[(size_t)m * K + k0 + c * 8];
    uint4 bv = *(const uint4*)&W[(size_t)(n0 + r) * K + k0 + c * 8];
    __syncthreads();
    *(uint4*)&As[r][c * 8] = av;
    *(uint4*)&Bs[r][c * 8] = bv;
    __syncthreads();
    s8v a0 = *(const s8v*)&As[mi + fr][quad * 8];
    s8v a1 = *(const s8v*)&As[mi + 16 + fr][quad * 8];
    s8v b0 = *(const s8v*)&Bs[ni + fr][quad * 8];
    s8v b1 = *(const s8v*)&Bs[ni + 16 + fr][quad * 8];
    c00 = __builtin_amdgcn_mfma_f32_16x16x32_bf16(a0, b0, c00, 0, 0, 0);
    c01 = __builtin_amdgcn_mfma_f32_16x16x32_bf16(a0, b1, c01, 0, 0, 0);
    c10 = __builtin_amdgcn_mfma_f32_16x16x32_bf16(a1, b0, c10, 0, 0, 0);
    c11 = __builtin_amdgcn_mfma_f32_16x16x32_bf16(a1, b1, c11, 0, 0, 0);
  }
  // C/D layout: col = lane&15, row = quad*4 + reg
  const int col = n0 + ni + fr;
#pragma unroll
  for (int i = 0; i < 4; ++i) {
    int row = m0 + mi + quad * 4 + i;
    if (row < M) {
      C[(size_t)row * Nout + col] = fb(c00[i]);
      C[(size_t)row * Nout + col + 16] = fb(c01[i]);
    }
    int row2 = row + 16;
    if (row2 < M) {
      C[(size_t)row2 * Nout + col] = fb(c10[i]);
      C[(size_t)row2 * Nout + col + 16] = fb(c11[i]);
    }
  }
}

// ---------- CSR build ----------
__global__ void k_hist(const int* __restrict__ ei, int* __restrict__ deg) {
  int e = blockIdx.x * 256 + threadIdx.x;
  if (e >= EP_EDGES) return;
  int d = (e < N_EDGES) ? ei[N_EDGES + e] : e - N_EDGES;
  atomicAdd(&deg[d], 1);
}

__global__ void k_scan_local(const int* __restrict__ deg,
                             int* __restrict__ rowstart,
                             int* __restrict__ bsum) {
  __shared__ int sh[256];
  const int tid = threadIdx.x;
  const int i = blockIdx.x * 256 + tid;
  int v = (i < N_NODES) ? deg[i] : 0;
  sh[tid] = v;
  __syncthreads();
  for (int off = 1; off < 256; off <<= 1) {
    int add = (tid >= off) ? sh[tid - off] : 0;
    __syncthreads();
    sh[tid] += add;
    __syncthreads();
  }
  if (i < N_NODES) rowstart[i] = sh[tid] - v;
  if (tid == 255) bsum[blockIdx.x] = sh[255];
}

__global__ void k_scan_bsum(int* __restrict__ bsum, int* __restrict__ boff) {
  __shared__ int sh[256];
  const int tid = threadIdx.x;
  int v = (tid < NBLK_SCAN) ? bsum[tid] : 0;
  sh[tid] = v;
  __syncthreads();
  for (int off = 1; off < 256; off <<= 1) {
    int add = (tid >= off) ? sh[tid - off] : 0;
    __syncthreads();
    sh[tid] += add;
    __syncthreads();
  }
  boff[tid] = sh[tid] - v;
}

__global__ void k_scan_add(int* __restrict__ rowstart,
                           const int* __restrict__ boff) {
  int i = blockIdx.x * 256 + threadIdx.x;
  if (i < N_NODES) rowstart[i] += boff[i >> 8];
  if (i == N_NODES) rowstart[N_NODES] = EP_EDGES;
}

__global__ void k_scatter(const int* __restrict__ ei,
                          const int* __restrict__ rowstart,
                          int* __restrict__ fill, int* __restrict__ esrc) {
  int e = blockIdx.x * 256 + threadIdx.x;
  if (e >= EP_EDGES) return;
  int s, d;
  if (e < N_EDGES) { s = ei[e]; d = ei[N_EDGES + e]; }
  else             { s = d = e - N_EDGES; }
  int pos = rowstart[d] + atomicAdd(&fill[d], 1);
  esrc[pos] = s;
}

// ---------- per-node attention scores ----------
__global__ void attn_scores(const u16* __restrict__ h,
                            const float* __restrict__ a_src,
                            const float* __restrict__ a_dst,
                            float* __restrict__ alo, float* __restrict__ ahi,
                            int HC, int H) {
  const int n = blockIdx.x;
  const int t = threadIdx.x;
  float v = bff(h[(size_t)n * HC + t]);
  float s = v * a_src[t];
  float d = v * a_dst[t];
#pragma unroll
  for (int off = 32; off; off >>= 1) {
    s += __shfl_down(s, off, 64);
    d += __shfl_down(d, off, 64);
  }
  if ((t & 63) == 0) {
    int hd = t >> 6;
    alo[n * H + hd] = s;
    ahi[n * H + hd] = d;
  }
}

// ---------- fused segment softmax -> alpha (one wave per dst) ----------
template <int H>
__global__ __launch_bounds__(64) void attn_alpha(
    const int* __restrict__ rowstart, const int* __restrict__ esrc,
    const float* __restrict__ alo, const float* __restrict__ ahi,
    float* __restrict__ abuf) {
  const int d = blockIdx.x;
  const int lane = threadIdx.x;
  const int s0 = rowstart[d], s1 = rowstart[d + 1];
  float ah[H];
#pragma unroll
  for (int h = 0; h < H; ++h) ah[h] = ahi[d * H + h];
  float mx[H];
#pragma unroll
  for (int h = 0; h < H; ++h) mx[h] = -1e30f;
  for (int i = s0 + lane; i < s1; i += 64) {
    int s = esrc[i];
#pragma unroll
    for (int h = 0; h < H; ++h) {
      float v = alo[s * H + h] + ah[h];
      v = v > 0.f ? v : 0.2f * v;
      mx[h] = fmaxf(mx[h], v);
    }
  }
#pragma unroll
  for (int off = 32; off; off >>= 1)
#pragma unroll
    for (int h = 0; h < H; ++h) mx[h] = fmaxf(mx[h], __shfl_xor(mx[h], off, 64));
  float sm[H] = {};
  for (int i = s0 + lane; i < s1; i += 64) {
    int s = esrc[i];
#pragma unroll
    for (int h = 0; h < H; ++h) {
      float v = alo[s * H + h] + ah[h];
      v = v > 0.f ? v : 0.2f * v;
      sm[h] += __expf(v - mx[h]);
    }
  }
#pragma unroll
  for (int off = 32; off; off >>= 1)
#pragma unroll
    for (int h = 0; h < H; ++h) sm[h] += __shfl_xor(sm[h], off, 64);
  float inv[H];
#pragma unroll
  for (int h = 0; h < H; ++h) inv[h] = 1.f / (sm[h] + 1e-16f);
  for (int i = s0 + lane; i < s1; i += 64) {
    int s = esrc[i];
#pragma unroll
    for (int h = 0; h < H; ++h) {
      float v = alo[s * H + h] + ah[h];
      v = v > 0.f ? v : 0.2f * v;
      abuf[i * H + h] = __expf(v - mx[h]) * inv[h];
    }
  }
}

// ---------- aggregation H=4: 128 thr/block, 2 channels/lane, bf16 gather ----
__global__ __launch_bounds__(128) void aggregate4(
    const int* __restrict__ rowstart, const int* __restrict__ esrc,
    const u16* __restrict__ hbuf, const float* __restrict__ abuf,
    const float* __restrict__ bias, u16* __restrict__ feat) {
  const int d = blockIdx.x;
  const int t = threadIdx.x;
  const int c = t * 2;
  const int head = t >> 5;
  const int s0 = rowstart[d], s1 = rowstart[d + 1];
  float a0 = 0.f, a1 = 0.f;
  for (int i = s0; i < s1; ++i) {
    int s = esrc[i];
    float al = abuf[i * 4 + head];
    unsigned hv = *(const unsigned*)&hbuf[(size_t)s * 256 + c];
    a0 += al * bff((u16)(hv & 0xffffu));
    a1 += al * bff((u16)(hv >> 16));
  }
  float v0 = a0 + bias[c], v1 = a1 + bias[c + 1];
  v0 = v0 > 0.f ? v0 : __expf(v0) - 1.f;
  v1 = v1 > 0.f ? v1 : __expf(v1) - 1.f;
  unsigned pv = (unsigned)fb(v0) | ((unsigned)fb(v1) << 16);
  *(unsigned*)&feat[(size_t)d * 256 + c] = pv;
}

// ---------- aggregation H=1 (final layer): f32 out ----------
__global__ __launch_bounds__(64) void aggregate1(
    const int* __restrict__ rowstart, const int* __restrict__ esrc,
    const u16* __restrict__ hbuf, const float* __restrict__ abuf,
    const float* __restrict__ bias, float* __restrict__ feat) {
  const int d = blockIdx.x;
  const int t = threadIdx.x;
  const int s0 = rowstart[d], s1 = rowstart[d + 1];
  float acc = 0.f;
  for (int i = s0; i < s1; ++i) {
    int s = esrc[i];
    acc += abuf[i] * bff(hbuf[(size_t)s * 64 + t]);
  }
  float v = acc + bias[t];
  feat[(size_t)d * 64 + t] = v > 0.f ? v : __expf(v) - 1.f;
}

// ---------- global mean pool ----------
__global__ void pool_acc(const float* __restrict__ feat,
                         const int* __restrict__ batch,
                         float* __restrict__ gsum, float* __restrict__ gcnt) {
  const int n = blockIdx.x;
  const int t = threadIdx.x;
  int b = batch[n];
  atomicAdd(&gsum[b * 64 + t], feat[n * 64 + t]);
  if (t == 0) atomicAdd(&gcnt[b], 1.f);
}

// ---------- fused MLP heads ----------
__global__ void heads(const float* __restrict__ gsum,
                      const float* __restrict__ gcnt,
                      const float* __restrict__ Wc1, const float* __restrict__ bc1,
                      const float* __restrict__ Wc2, const float* __restrict__ bc2,
                      const float* __restrict__ Wr1, const float* __restrict__ br1,
                      const float* __restrict__ Wr2, const float* __restrict__ br2,
                      float* __restrict__ out) {
  __shared__ float g[64];
  const int gi = blockIdx.x, j = threadIdx.x;
  float cnt = gcnt[gi];
  cnt = cnt < 1.f ? 1.f : cnt;
  g[j] = gsum[gi * 64 + j] / cnt;
  __syncthreads();
  float hc = bc1[j], hr = br1[j];
#pragma unroll 8
  for (int c = 0; c < 64; ++c) {
    float gv = g[c];
    hc += gv * Wc1[j * 64 + c];
    hr += gv * Wr1[j * 64 + c];
  }
  hc = fmaxf(hc, 0.f) * Wc2[j];
  hr = fmaxf(hr, 0.f) * Wr2[j];
#pragma unroll
  for (int off = 32; off; off >>= 1) {
    hc += __shfl_down(hc, off, 64);
    hr += __shfl_down(hr, off, 64);
  }
  if (j == 0) {
    out[gi] = hc + bc2[0];
    out[N_GRAPHS + gi] = hr + br2[0];
  }
}

extern "C" void kernel_launch(void* const* d_in, const int* in_sizes, int n_in,
                              void* d_out, int out_size, void* d_ws,
                              size_t ws_size, hipStream_t stream) {
  const float* x   = (const float*)d_in[0];
  const int* ei    = (const int*)d_in[1];
  const int* batch = (const int*)d_in[2];
  const float* W1  = (const float*)d_in[3];
  const float* as1 = (const float*)d_in[4];
  const float* ad1 = (const float*)d_in[5];
  const float* b1  = (const float*)d_in[6];
  const float* W2  = (const float*)d_in[7];
  const float* as2 = (const float*)d_in[8];
  const float* ad2 = (const float*)d_in[9];
  const float* b2  = (const float*)d_in[10];
  const float* W3  = (const float*)d_in[11];
  const float* as3 = (const float*)d_in[12];
  const float* ad3 = (const float*)d_in[13];
  const float* b3  = (const float*)d_in[14];
  const float* Wc1 = (const float*)d_in[15];
  const float* bc1 = (const float*)d_in[16];
  const float* Wc2 = (const float*)d_in[17];
  const float* bc2 = (const float*)d_in[18];
  const float* Wr1 = (const float*)d_in[19];
  const float* br1 = (const float*)d_in[20];
  const float* Wr2 = (const float*)d_in[21];
  const float* br2 = (const float*)d_in[22];
  float* out = (float*)d_out;

  // ---- workspace layout (float units; all offsets multiples of 4 -> 16B) ----
  float* ws = (float*)d_ws;
  u16* h_buf = (u16*)ws;                              // N*256 u16 = N*128 f
  float* p = ws + (size_t)N_NODES * 128;
  u16* featb = (u16*)p;                               // N*256 u16
  p += (size_t)N_NODES * 128;
  u16* xb = (u16*)p;                                  // N*128 u16
  p += (size_t)N_NODES * 64;
  u16* W1b = (u16*)p; p += 16384;                     // 256*128 u16
  u16* W2b = (u16*)p; p += 32768;                     // 256*256 u16
  u16* W3b = (u16*)p; p += 8192;                      // 64*256 u16
  float* feat3 = p;   p += (size_t)N_NODES * 64;      // f32
  float* abuf  = p;   p += (size_t)EP_EDGES * 4;
  float* alo   = p;   p += (size_t)N_NODES * 4;
  float* ahi   = p;   p += (size_t)N_NODES * 4;
  int* rowstart = (int*)p; p += (N_NODES + 4);
  int* esrc    = (int*)p;  p += EP_EDGES;
  float* gsum  = p;   p += N_GRAPHS * 64;
  float* gcnt  = p;
  // build-time aliases
  int* deg  = (int*)alo;
  int* fill = (int*)ahi;
  int* bsum = (int*)gsum;
  int* boff = (int*)gsum + 256;

  // ---- CSR build ----
  hipMemsetAsync(deg, 0, (size_t)N_NODES * 4, stream);
  hipMemsetAsync(fill, 0, (size_t)N_NODES * 4, stream);
  const int eblk = (EP_EDGES + 255) / 256;
  k_hist<<<eblk, 256, 0, stream>>>(ei, deg);
  k_scan_local<<<NBLK_SCAN, 256, 0, stream>>>(deg, rowstart, bsum);
  k_scan_bsum<<<1, 256, 0, stream>>>(bsum, boff);
  k_scan_add<<<(N_NODES + 256) / 256, 256, 0, stream>>>(rowstart, boff);
  k_scatter<<<eblk, 256, 0, stream>>>(ei, rowstart, fill, esrc);

  // ---- input/weight bf16 conversion ----
  f2b<<<(N_NODES * 128 + 255) / 256, 256, 0, stream>>>(x, xb, N_NODES * 128);
  f2b<<<(32768 + 255) / 256, 256, 0, stream>>>(W1, W1b, 32768);
  f2b<<<(65536 + 255) / 256, 256, 0, stream>>>(W2, W2b, 65536);
  f2b<<<(16384 + 255) / 256, 256, 0, stream>>>(W3, W3b, 16384);

  const int MB = (N_NODES + 63) / 64;
  // ---- layer 1: xb[N,128] -> featb[N,256] ----
  gemm_bf16<<<dim3(4, MB), 256, 0, stream>>>(xb, W1b, h_buf, N_NODES, 256, 128);
  attn_scores<<<N_NODES, 256, 0, stream>>>(h_buf, as1, ad1, alo, ahi, 256, 4);
  attn_alpha<4><<<N_NODES, 64, 0, stream>>>(rowstart, esrc, alo, ahi, abuf);
  aggregate4<<<N_NODES, 128, 0, stream>>>(rowstart, esrc, h_buf, abuf, b1, featb);
  // ---- layer 2: featb -> featb ----
  gemm_bf16<<<dim3(4, MB), 256, 0, stream>>>(featb, W2b, h_buf, N_NODES, 256, 256);
  attn_scores<<<N_NODES, 256, 0, stream>>>(h_buf, as2, ad2, alo, ahi, 256, 4);
  attn_alpha<4><<<N_NODES, 64, 0, stream>>>(rowstart, esrc, alo, ahi, abuf);
  aggregate4<<<N_NODES, 128, 0, stream>>>(rowstart, esrc, h_buf, abuf, b2, featb);
  // ---- layer 3: featb -> feat3[N,64] ----
  gemm_bf16<<<dim3(1, MB), 256, 0, stream>>>(featb, W3b, h_buf, N_NODES, 64, 256);
  attn_scores<<<N_NODES, 64, 0, stream>>>(h_buf, as3, ad3, alo, ahi, 64, 1);
  attn_alpha<1><<<N_NODES, 64, 0, stream>>>(rowstart, esrc, alo, ahi, abuf);
  aggregate1<<<N_NODES, 64, 0, stream>>>(rowstart, esrc, h_buf, abuf, b3, feat3);

  // ---- global mean pool + heads ----
  hipMemsetAsync(gsum, 0, (size_t)N_GRAPHS * 64 * 4, stream);
  hipMemsetAsync(gcnt, 0, (size_t)N_GRAPHS * 4, stream);
  pool_acc<<<N_NODES, 64, 0, stream>>>(feat3, batch, gsum, gcnt);
  heads<<<N_GRAPHS, 64, 0, stream>>>(gsum, gcnt, Wc1, bc1, Wc2, bc2, Wr1, br1,
                                     Wr2, br2, out);
}

// Round 4
// 712.648 us; speedup vs baseline: 3.3815x; 1.1282x over previous
//
#include <hip/hip_runtime.h>

#define N_NODES 50000
#define N_EDGES 800000
#define EP_EDGES (N_EDGES + N_NODES)
#define N_GRAPHS 256
#define NBLK_SCAN ((N_NODES + 255) / 256)
#define POOL_CHUNK ((N_NODES + 255) / 256)

typedef unsigned short u16;
typedef __attribute__((ext_vector_type(8))) short s8v;    // 8 x bf16 (4 VGPRs)
typedef __attribute__((ext_vector_type(4))) float f4v;    // mfma accumulator

// ---------- bf16 helpers (RNE) ----------
__device__ __forceinline__ u16 fb(float f) {
  unsigned u = __float_as_uint(f);
  return (u16)((u + 0x7fffu + ((u >> 16) & 1u)) >> 16);
}
__device__ __forceinline__ float bff(u16 s) {
  return __uint_as_float(((unsigned)s) << 16);
}

__global__ void f2b(const float* __restrict__ in, u16* __restrict__ o, int n) {
  int i = blockIdx.x * 256 + threadIdx.x;
  if (i < n) o[i] = fb(in[i]);
}

// ---------- bf16 MFMA GEMM: C[M,Nout](bf16) = A[M,K](bf16) * W[Nout,K](bf16)^T
__global__ __launch_bounds__(256) void gemm_bf16(
    const u16* __restrict__ A, const u16* __restrict__ W,
    u16* __restrict__ C, int M, int Nout, int K) {
  __shared__ u16 As[64][40];
  __shared__ u16 Bs[64][40];
  const int t = threadIdx.x;
  const int m0 = blockIdx.y * 64, n0 = blockIdx.x * 64;
  const int r = t >> 2, c = t & 3;
  const int w = t >> 6, lane = t & 63;
  const int mi = (w & 1) * 32, ni = (w >> 1) * 32;
  const int quad = lane >> 4, fr = lane & 15;

  f4v c00{}, c01{}, c10{}, c11{};
  for (int k0 = 0; k0 < K; k0 += 32) {
    uint4 av = make_uint4(0, 0, 0, 0);
    int m = m0 + r;
    if (m < M) av = *(const uint4*)&A[(size_t)m * K + k0 + c * 8];
    uint4 bv = *(const uint4*)&W[(size_t)(n0 + r) * K + k0 + c * 8];
    __syncthreads();
    *(uint4*)&As[r][c * 8] = av;
    *(uint4*)&Bs[r][c * 8] = bv;
    __syncthreads();
    s8v a0 = *(const s8v*)&As[mi + fr][quad * 8];
    s8v a1 = *(const s8v*)&As[mi + 16 + fr][quad * 8];
    s8v b0 = *(const s8v*)&Bs[ni + fr][quad * 8];
    s8v b1 = *(const s8v*)&Bs[ni + 16 + fr][quad * 8];
    c00 = __builtin_amdgcn_mfma_f32_16x16x32_bf16(a0, b0, c00, 0, 0, 0);
    c01 = __builtin_amdgcn_mfma_f32_16x16x32_bf16(a0, b1, c01, 0, 0, 0);
    c10 = __builtin_amdgcn_mfma_f32_16x16x32_bf16(a1, b0, c10, 0, 0, 0);
    c11 = __builtin_amdgcn_mfma_f32_16x16x32_bf16(a1, b1, c11, 0, 0, 0);
  }
  const int col = n0 + ni + fr;
#pragma unroll
  for (int i = 0; i < 4; ++i) {
    int row = m0 + mi + quad * 4 + i;
    if (row < M) {
      C[(size_t)row * Nout + col] = fb(c00[i]);
      C[(size_t)row * Nout + col + 16] = fb(c01[i]);
    }
    int row2 = row + 16;
    if (row2 < M) {
      C[(size_t)row2 * Nout + col] = fb(c10[i]);
      C[(size_t)row2 * Nout + col + 16] = fb(c11[i]);
    }
  }
}

// ---------- CSR build ----------
__global__ void k_hist(const int* __restrict__ ei, int* __restrict__ deg) {
  int e = blockIdx.x * 256 + threadIdx.x;
  if (e >= EP_EDGES) return;
  int d = (e < N_EDGES) ? ei[N_EDGES + e] : e - N_EDGES;
  atomicAdd(&deg[d], 1);
}

__global__ void k_scan_local(const int* __restrict__ deg,
                             int* __restrict__ rowstart,
                             int* __restrict__ bsum) {
  __shared__ int sh[256];
  const int tid = threadIdx.x;
  const int i = blockIdx.x * 256 + tid;
  int v = (i < N_NODES) ? deg[i] : 0;
  sh[tid] = v;
  __syncthreads();
  for (int off = 1; off < 256; off <<= 1) {
    int add = (tid >= off) ? sh[tid - off] : 0;
    __syncthreads();
    sh[tid] += add;
    __syncthreads();
  }
  if (i < N_NODES) rowstart[i] = sh[tid] - v;
  if (tid == 255) bsum[blockIdx.x] = sh[255];
}

__global__ void k_scan_bsum(int* __restrict__ bsum, int* __restrict__ boff) {
  __shared__ int sh[256];
  const int tid = threadIdx.x;
  int v = (tid < NBLK_SCAN) ? bsum[tid] : 0;
  sh[tid] = v;
  __syncthreads();
  for (int off = 1; off < 256; off <<= 1) {
    int add = (tid >= off) ? sh[tid - off] : 0;
    __syncthreads();
    sh[tid] += add;
    __syncthreads();
  }
  boff[tid] = sh[tid] - v;
}

__global__ void k_scan_add(int* __restrict__ rowstart,
                           const int* __restrict__ boff) {
  int i = blockIdx.x * 256 + threadIdx.x;
  if (i < N_NODES) rowstart[i] += boff[i >> 8];
  if (i == N_NODES) rowstart[N_NODES] = EP_EDGES;
}

__global__ void k_scatter(const int* __restrict__ ei,
                          const int* __restrict__ rowstart,
                          int* __restrict__ fill, int* __restrict__ esrc) {
  int e = blockIdx.x * 256 + threadIdx.x;
  if (e >= EP_EDGES) return;
  int s, d;
  if (e < N_EDGES) { s = ei[e]; d = ei[N_EDGES + e]; }
  else             { s = d = e - N_EDGES; }
  int pos = rowstart[d] + atomicAdd(&fill[d], 1);
  esrc[pos] = s;
}

// ---------- per-node attention scores ----------
__global__ void attn_scores(const u16* __restrict__ h,
                            const float* __restrict__ a_src,
                            const float* __restrict__ a_dst,
                            float* __restrict__ alo, float* __restrict__ ahi,
                            int HC, int H) {
  const int n = blockIdx.x;
  const int t = threadIdx.x;
  float v = bff(h[(size_t)n * HC + t]);
  float s = v * a_src[t];
  float d = v * a_dst[t];
#pragma unroll
  for (int off = 32; off; off >>= 1) {
    s += __shfl_down(s, off, 64);
    d += __shfl_down(d, off, 64);
  }
  if ((t & 63) == 0) {
    int hd = t >> 6;
    alo[n * H + hd] = s;
    ahi[n * H + hd] = d;
  }
}

// ---------- fused segment softmax -> alpha ----------
template <int H>
__global__ __launch_bounds__(64) void attn_alpha(
    const int* __restrict__ rowstart, const int* __restrict__ esrc,
    const float* __restrict__ alo, const float* __restrict__ ahi,
    float* __restrict__ abuf) {
  const int d = blockIdx.x;
  const int lane = threadIdx.x;
  const int s0 = rowstart[d], s1 = rowstart[d + 1];
  float ah[H];
#pragma unroll
  for (int h = 0; h < H; ++h) ah[h] = ahi[d * H + h];
  float mx[H];
#pragma unroll
  for (int h = 0; h < H; ++h) mx[h] = -1e30f;
  for (int i = s0 + lane; i < s1; i += 64) {
    int s = esrc[i];
#pragma unroll
    for (int h = 0; h < H; ++h) {
      float v = alo[s * H + h] + ah[h];
      v = v > 0.f ? v : 0.2f * v;
      mx[h] = fmaxf(mx[h], v);
    }
  }
#pragma unroll
  for (int off = 32; off; off >>= 1)
#pragma unroll
    for (int h = 0; h < H; ++h) mx[h] = fmaxf(mx[h], __shfl_xor(mx[h], off, 64));
  float sm[H] = {};
  for (int i = s0 + lane; i < s1; i += 64) {
    int s = esrc[i];
#pragma unroll
    for (int h = 0; h < H; ++h) {
      float v = alo[s * H + h] + ah[h];
      v = v > 0.f ? v : 0.2f * v;
      sm[h] += __expf(v - mx[h]);
    }
  }
#pragma unroll
  for (int off = 32; off; off >>= 1)
#pragma unroll
    for (int h = 0; h < H; ++h) sm[h] += __shfl_xor(sm[h], off, 64);
  float inv[H];
#pragma unroll
  for (int h = 0; h < H; ++h) inv[h] = 1.f / (sm[h] + 1e-16f);
  for (int i = s0 + lane; i < s1; i += 64) {
    int s = esrc[i];
#pragma unroll
    for (int h = 0; h < H; ++h) {
      float v = alo[s * H + h] + ah[h];
      v = v > 0.f ? v : 0.2f * v;
      abuf[i * H + h] = __expf(v - mx[h]) * inv[h];
    }
  }
}

// ---------- aggregation H=4 ----------
__global__ __launch_bounds__(128) void aggregate4(
    const int* __restrict__ rowstart, const int* __restrict__ esrc,
    const u16* __restrict__ hbuf, const float* __restrict__ abuf,
    const float* __restrict__ bias, u16* __restrict__ feat) {
  const int d = blockIdx.x;
  const int t = threadIdx.x;
  const int c = t * 2;
  const int head = t >> 5;
  const int s0 = rowstart[d], s1 = rowstart[d + 1];
  float a0 = 0.f, a1 = 0.f;
  for (int i = s0; i < s1; ++i) {
    int s = esrc[i];
    float al = abuf[i * 4 + head];
    unsigned hv = *(const unsigned*)&hbuf[(size_t)s * 256 + c];
    a0 += al * bff((u16)(hv & 0xffffu));
    a1 += al * bff((u16)(hv >> 16));
  }
  float v0 = a0 + bias[c], v1 = a1 + bias[c + 1];
  v0 = v0 > 0.f ? v0 : __expf(v0) - 1.f;
  v1 = v1 > 0.f ? v1 : __expf(v1) - 1.f;
  unsigned pv = (unsigned)fb(v0) | ((unsigned)fb(v1) << 16);
  *(unsigned*)&feat[(size_t)d * 256 + c] = pv;
}

// ---------- aggregation H=1 (final layer): f32 out ----------
__global__ __launch_bounds__(64) void aggregate1(
    const int* __restrict__ rowstart, const int* __restrict__ esrc,
    const u16* __restrict__ hbuf, const float* __restrict__ abuf,
    const float* __restrict__ bias, float* __restrict__ feat) {
  const int d = blockIdx.x;
  const int t = threadIdx.x;
  const int s0 = rowstart[d], s1 = rowstart[d + 1];
  float acc = 0.f;
  for (int i = s0; i < s1; ++i) {
    int s = esrc[i];
    acc += abuf[i] * bff(hbuf[(size_t)s * 64 + t]);
  }
  float v = acc + bias[t];
  feat[(size_t)d * 64 + t] = v > 0.f ? v : __expf(v) - 1.f;
}

// ---------- segmented global mean pool (batch_idx sorted) ----------
// 256 blocks x 64 threads; each block owns a contiguous node slice and
// flushes one atomic per (graph transition, channel).
__global__ __launch_bounds__(64) void pool_seg(
    const float* __restrict__ feat, const int* __restrict__ batch,
    float* __restrict__ gsum, float* __restrict__ gcnt) {
  const int b = blockIdx.x;
  const int t = threadIdx.x;
  int n0 = b * POOL_CHUNK;
  int n1 = n0 + POOL_CHUNK;
  if (n1 > N_NODES) n1 = N_NODES;
  if (n0 >= n1) return;
  int g = batch[n0];
  float acc = 0.f;
  int cnt = 0;
  for (int n = n0; n < n1; ++n) {
    int gn = batch[n];
    if (gn != g) {
      atomicAdd(&gsum[g * 64 + t], acc);
      if (t == 0) atomicAdd(&gcnt[g], (float)cnt);
      acc = 0.f; cnt = 0; g = gn;
    }
    acc += feat[(size_t)n * 64 + t];
    ++cnt;
  }
  atomicAdd(&gsum[g * 64 + t], acc);
  if (t == 0) atomicAdd(&gcnt[g], (float)cnt);
}

// ---------- fused MLP heads ----------
__global__ void heads(const float* __restrict__ gsum,
                      const float* __restrict__ gcnt,
                      const float* __restrict__ Wc1, const float* __restrict__ bc1,
                      const float* __restrict__ Wc2, const float* __restrict__ bc2,
                      const float* __restrict__ Wr1, const float* __restrict__ br1,
                      const float* __restrict__ Wr2, const float* __restrict__ br2,
                      float* __restrict__ out) {
  __shared__ float g[64];
  const int gi = blockIdx.x, j = threadIdx.x;
  float cnt = gcnt[gi];
  cnt = cnt < 1.f ? 1.f : cnt;
  g[j] = gsum[gi * 64 + j] / cnt;
  __syncthreads();
  float hc = bc1[j], hr = br1[j];
#pragma unroll 8
  for (int c = 0; c < 64; ++c) {
    float gv = g[c];
    hc += gv * Wc1[j * 64 + c];
    hr += gv * Wr1[j * 64 + c];
  }
  hc = fmaxf(hc, 0.f) * Wc2[j];
  hr = fmaxf(hr, 0.f) * Wr2[j];
#pragma unroll
  for (int off = 32; off; off >>= 1) {
    hc += __shfl_down(hc, off, 64);
    hr += __shfl_down(hr, off, 64);
  }
  if (j == 0) {
    out[gi] = hc + bc2[0];
    out[N_GRAPHS + gi] = hr + br2[0];
  }
}

extern "C" void kernel_launch(void* const* d_in, const int* in_sizes, int n_in,
                              void* d_out, int out_size, void* d_ws,
                              size_t ws_size, hipStream_t stream) {
  const float* x   = (const float*)d_in[0];
  const int* ei    = (const int*)d_in[1];
  const int* batch = (const int*)d_in[2];
  const float* W1  = (const float*)d_in[3];
  const float* as1 = (const float*)d_in[4];
  const float* ad1 = (const float*)d_in[5];
  const float* b1  = (const float*)d_in[6];
  const float* W2  = (const float*)d_in[7];
  const float* as2 = (const float*)d_in[8];
  const float* ad2 = (const float*)d_in[9];
  const float* b2  = (const float*)d_in[10];
  const float* W3  = (const float*)d_in[11];
  const float* as3 = (const float*)d_in[12];
  const float* ad3 = (const float*)d_in[13];
  const float* b3  = (const float*)d_in[14];
  const float* Wc1 = (const float*)d_in[15];
  const float* bc1 = (const float*)d_in[16];
  const float* Wc2 = (const float*)d_in[17];
  const float* bc2 = (const float*)d_in[18];
  const float* Wr1 = (const float*)d_in[19];
  const float* br1 = (const float*)d_in[20];
  const float* Wr2 = (const float*)d_in[21];
  const float* br2 = (const float*)d_in[22];
  float* out = (float*)d_out;

  // ---- workspace layout ----
  float* ws = (float*)d_ws;
  u16* h_buf = (u16*)ws;
  float* p = ws + (size_t)N_NODES * 128;
  u16* featb = (u16*)p;
  p += (size_t)N_NODES * 128;
  u16* xb = (u16*)p;
  p += (size_t)N_NODES * 64;
  u16* W1b = (u16*)p; p += 16384;
  u16* W2b = (u16*)p; p += 32768;
  u16* W3b = (u16*)p; p += 8192;
  float* feat3 = p;   p += (size_t)N_NODES * 64;
  float* abuf  = p;   p += (size_t)EP_EDGES * 4;
  float* alo   = p;   p += (size_t)N_NODES * 4;
  float* ahi   = p;   p += (size_t)N_NODES * 4;
  int* rowstart = (int*)p; p += (N_NODES + 4);
  int* esrc    = (int*)p;  p += EP_EDGES;
  float* gsum  = p;   p += N_GRAPHS * 64;
  float* gcnt  = p;
  int* deg  = (int*)alo;
  int* fill = (int*)ahi;
  int* bsum = (int*)gsum;
  int* boff = (int*)gsum + 256;

  // ---- CSR build ----
  hipMemsetAsync(deg, 0, (size_t)N_NODES * 4, stream);
  hipMemsetAsync(fill, 0, (size_t)N_NODES * 4, stream);
  const int eblk = (EP_EDGES + 255) / 256;
  k_hist<<<eblk, 256, 0, stream>>>(ei, deg);
  k_scan_local<<<NBLK_SCAN, 256, 0, stream>>>(deg, rowstart, bsum);
  k_scan_bsum<<<1, 256, 0, stream>>>(bsum, boff);
  k_scan_add<<<(N_NODES + 256) / 256, 256, 0, stream>>>(rowstart, boff);
  k_scatter<<<eblk, 256, 0, stream>>>(ei, rowstart, fill, esrc);

  // ---- input/weight bf16 conversion ----
  f2b<<<(N_NODES * 128 + 255) / 256, 256, 0, stream>>>(x, xb, N_NODES * 128);
  f2b<<<(32768 + 255) / 256, 256, 0, stream>>>(W1, W1b, 32768);
  f2b<<<(65536 + 255) / 256, 256, 0, stream>>>(W2, W2b, 65536);
  f2b<<<(16384 + 255) / 256, 256, 0, stream>>>(W3, W3b, 16384);

  const int MB = (N_NODES + 63) / 64;
  // ---- layer 1 ----
  gemm_bf16<<<dim3(4, MB), 256, 0, stream>>>(xb, W1b, h_buf, N_NODES, 256, 128);
  attn_scores<<<N_NODES, 256, 0, stream>>>(h_buf, as1, ad1, alo, ahi, 256, 4);
  attn_alpha<4><<<N_NODES, 64, 0, stream>>>(rowstart, esrc, alo, ahi, abuf);
  aggregate4<<<N_NODES, 128, 0, stream>>>(rowstart, esrc, h_buf, abuf, b1, featb);
  // ---- layer 2 ----
  gemm_bf16<<<dim3(4, MB), 256, 0, stream>>>(featb, W2b, h_buf, N_NODES, 256, 256);
  attn_scores<<<N_NODES, 256, 0, stream>>>(h_buf, as2, ad2, alo, ahi, 256, 4);
  attn_alpha<4><<<N_NODES, 64, 0, stream>>>(rowstart, esrc, alo, ahi, abuf);
  aggregate4<<<N_NODES, 128, 0, stream>>>(rowstart, esrc, h_buf, abuf, b2, featb);
  // ---- layer 3 ----
  gemm_bf16<<<dim3(1, MB), 256, 0, stream>>>(featb, W3b, h_buf, N_NODES, 64, 256);
  attn_scores<<<N_NODES, 64, 0, stream>>>(h_buf, as3, ad3, alo, ahi, 64, 1);
  attn_alpha<1><<<N_NODES, 64, 0, stream>>>(rowstart, esrc, alo, ahi, abuf);
  aggregate1<<<N_NODES, 64, 0, stream>>>(rowstart, esrc, h_buf, abuf, b3, feat3);

  // ---- segmented mean pool + heads ----
  hipMemsetAsync(gsum, 0, (size_t)N_GRAPHS * 64 * 4, stream);
  hipMemsetAsync(gcnt, 0, (size_t)N_GRAPHS * 4, stream);
  pool_seg<<<N_GRAPHS, 64, 0, stream>>>(feat3, batch, gsum, gcnt);
  heads<<<N_GRAPHS, 64, 0, stream>>>(gsum, gcnt, Wc1, bc1, Wc2, bc2, Wr1, br1,
                                     Wr2, br2, out);
}

// Round 5
// 595.182 us; speedup vs baseline: 4.0489x; 1.1974x over previous
//
#include <hip/hip_runtime.h>

#define N_NODES 50000
#define N_EDGES 800000
#define EP_EDGES (N_EDGES + N_NODES)
#define N_GRAPHS 256
#define NBLK_SCAN ((N_NODES + 255) / 256)
#define POOL_CHUNK ((N_NODES + 255) / 256)

typedef unsigned short u16;
typedef __attribute__((ext_vector_type(8))) short s8v;    // 8 x bf16 (4 VGPRs)
typedef __attribute__((ext_vector_type(4))) float f4v;    // mfma accumulator

// ---------- bf16 helpers (RNE) ----------
__device__ __forceinline__ u16 fb(float f) {
  unsigned u = __float_as_uint(f);
  return (u16)((u + 0x7fffu + ((u >> 16) & 1u)) >> 16);
}
__device__ __forceinline__ float bff(u16 s) {
  return __uint_as_float(((unsigned)s) << 16);
}

__global__ void f2b(const float* __restrict__ in, u16* __restrict__ o, int n) {
  int i = blockIdx.x * 256 + threadIdx.x;
  if (i < n) o[i] = fb(in[i]);
}

// ---------- bf16 MFMA GEMM: C[M,Nout](bf16) = A[M,K](bf16) * W[Nout,K](bf16)^T
__global__ __launch_bounds__(256) void gemm_bf16(
    const u16* __restrict__ A, const u16* __restrict__ W,
    u16* __restrict__ C, int M, int Nout, int K) {
  __shared__ u16 As[64][40];
  __shared__ u16 Bs[64][40];
  const int t = threadIdx.x;
  const int m0 = blockIdx.y * 64, n0 = blockIdx.x * 64;
  const int r = t >> 2, c = t & 3;
  const int w = t >> 6, lane = t & 63;
  const int mi = (w & 1) * 32, ni = (w >> 1) * 32;
  const int quad = lane >> 4, fr = lane & 15;

  f4v c00{}, c01{}, c10{}, c11{};
  for (int k0 = 0; k0 < K; k0 += 32) {
    uint4 av = make_uint4(0, 0, 0, 0);
    int m = m0 + r;
    if (m < M) av = *(const uint4*)&A[(size_t)m * K + k0 + c * 8];
    uint4 bv = *(const uint4*)&W[(size_t)(n0 + r) * K + k0 + c * 8];
    __syncthreads();
    *(uint4*)&As[r][c * 8] = av;
    *(uint4*)&Bs[r][c * 8] = bv;
    __syncthreads();
    s8v a0 = *(const s8v*)&As[mi + fr][quad * 8];
    s8v a1 = *(const s8v*)&As[mi + 16 + fr][quad * 8];
    s8v b0 = *(const s8v*)&Bs[ni + fr][quad * 8];
    s8v b1 = *(const s8v*)&Bs[ni + 16 + fr][quad * 8];
    c00 = __builtin_amdgcn_mfma_f32_16x16x32_bf16(a0, b0, c00, 0, 0, 0);
    c01 = __builtin_amdgcn_mfma_f32_16x16x32_bf16(a0, b1, c01, 0, 0, 0);
    c10 = __builtin_amdgcn_mfma_f32_16x16x32_bf16(a1, b0, c10, 0, 0, 0);
    c11 = __builtin_amdgcn_mfma_f32_16x16x32_bf16(a1, b1, c11, 0, 0, 0);
  }
  const int col = n0 + ni + fr;
#pragma unroll
  for (int i = 0; i < 4; ++i) {
    int row = m0 + mi + quad * 4 + i;
    if (row < M) {
      C[(size_t)row * Nout + col] = fb(c00[i]);
      C[(size_t)row * Nout + col + 16] = fb(c01[i]);
    }
    int row2 = row + 16;
    if (row2 < M) {
      C[(size_t)row2 * Nout + col] = fb(c10[i]);
      C[(size_t)row2 * Nout + col + 16] = fb(c11[i]);
    }
  }
}

// ---------- CSR build ----------
__global__ void k_hist(const int* __restrict__ ei, int* __restrict__ deg) {
  int e = blockIdx.x * 256 + threadIdx.x;
  if (e >= EP_EDGES) return;
  int d = (e < N_EDGES) ? ei[N_EDGES + e] : e - N_EDGES;
  atomicAdd(&deg[d], 1);
}

__global__ void k_scan_local(const int* __restrict__ deg,
                             int* __restrict__ rowstart,
                             int* __restrict__ bsum) {
  __shared__ int sh[256];
  const int tid = threadIdx.x;
  const int i = blockIdx.x * 256 + tid;
  int v = (i < N_NODES) ? deg[i] : 0;
  sh[tid] = v;
  __syncthreads();
  for (int off = 1; off < 256; off <<= 1) {
    int add = (tid >= off) ? sh[tid - off] : 0;
    __syncthreads();
    sh[tid] += add;
    __syncthreads();
  }
  if (i < N_NODES) rowstart[i] = sh[tid] - v;
  if (tid == 255) bsum[blockIdx.x] = sh[255];
}

__global__ void k_scan_bsum(int* __restrict__ bsum, int* __restrict__ boff) {
  __shared__ int sh[256];
  const int tid = threadIdx.x;
  int v = (tid < NBLK_SCAN) ? bsum[tid] : 0;
  sh[tid] = v;
  __syncthreads();
  for (int off = 1; off < 256; off <<= 1) {
    int add = (tid >= off) ? sh[tid - off] : 0;
    __syncthreads();
    sh[tid] += add;
    __syncthreads();
  }
  boff[tid] = sh[tid] - v;
}

__global__ void k_scan_add(int* __restrict__ rowstart,
                           const int* __restrict__ boff) {
  int i = blockIdx.x * 256 + threadIdx.x;
  if (i < N_NODES) rowstart[i] += boff[i >> 8];
  if (i == N_NODES) rowstart[N_NODES] = EP_EDGES;
}

__global__ void k_scatter(const int* __restrict__ ei,
                          const int* __restrict__ rowstart,
                          int* __restrict__ fill, int* __restrict__ esrc) {
  int e = blockIdx.x * 256 + threadIdx.x;
  if (e >= EP_EDGES) return;
  int s, d;
  if (e < N_EDGES) { s = ei[e]; d = ei[N_EDGES + e]; }
  else             { s = d = e - N_EDGES; }
  int pos = rowstart[d] + atomicAdd(&fill[d], 1);
  esrc[pos] = s;
}

// ---------- per-node attention scores ----------
__global__ void attn_scores(const u16* __restrict__ h,
                            const float* __restrict__ a_src,
                            const float* __restrict__ a_dst,
                            float* __restrict__ alo, float* __restrict__ ahi,
                            int HC, int H) {
  const int n = blockIdx.x;
  const int t = threadIdx.x;
  float v = bff(h[(size_t)n * HC + t]);
  float s = v * a_src[t];
  float d = v * a_dst[t];
#pragma unroll
  for (int off = 32; off; off >>= 1) {
    s += __shfl_down(s, off, 64);
    d += __shfl_down(d, off, 64);
  }
  if ((t & 63) == 0) {
    int hd = t >> 6;
    alo[n * H + hd] = s;
    ahi[n * H + hd] = d;
  }
}

// ---------- fused online-softmax aggregation, H=4 ----------
// 128 thr/block (one dst), lane owns 2 channels; unroll-4 batched gathers.
__global__ __launch_bounds__(128) void agg_fused4(
    const int* __restrict__ rowstart, const int* __restrict__ esrc,
    const u16* __restrict__ hbuf, const float* __restrict__ alo,
    const float* __restrict__ ahi, const float* __restrict__ bias,
    u16* __restrict__ feat) {
  const int d = blockIdx.x;
  const int t = threadIdx.x;
  const int c = t * 2;
  const int head = t >> 5;
  const int s0 = rowstart[d], s1 = rowstart[d + 1];
  const float ah = ahi[d * 4 + head];
  float m = -1e30f, l = 0.f, o0 = 0.f, o1 = 0.f;
  for (int i = s0; i < s1; i += 4) {
    float av[4];
    unsigned hv[4];
#pragma unroll
    for (int j = 0; j < 4; ++j) {
      if (i + j < s1) {
        int s = esrc[i + j];
        av[j] = alo[s * 4 + head];
        hv[j] = *(const unsigned*)&hbuf[(size_t)s * 256 + c];
      } else {
        av[j] = -1e38f;  // lrelu -> -2e37: exp weight 0, no branch needed
        hv[j] = 0;
      }
    }
#pragma unroll
    for (int j = 0; j < 4; ++j) {
      float e = av[j] + ah;
      e = e > 0.f ? e : 0.2f * e;
      float mn = fmaxf(m, e);
      float sc = __expf(m - mn);
      float w = __expf(e - mn);
      l = l * sc + w;
      o0 = o0 * sc + w * bff((u16)(hv[j] & 0xffffu));
      o1 = o1 * sc + w * bff((u16)(hv[j] >> 16));
      m = mn;
    }
  }
  float inv = 1.f / (l + 1e-16f);
  float v0 = o0 * inv + bias[c], v1 = o1 * inv + bias[c + 1];
  v0 = v0 > 0.f ? v0 : __expf(v0) - 1.f;
  v1 = v1 > 0.f ? v1 : __expf(v1) - 1.f;
  unsigned pv = (unsigned)fb(v0) | ((unsigned)fb(v1) << 16);
  *(unsigned*)&feat[(size_t)d * 256 + c] = pv;
}

// ---------- fused online-softmax aggregation, H=1 (f32 out) ----------
__global__ __launch_bounds__(64) void agg_fused1(
    const int* __restrict__ rowstart, const int* __restrict__ esrc,
    const u16* __restrict__ hbuf, const float* __restrict__ alo,
    const float* __restrict__ ahi, const float* __restrict__ bias,
    float* __restrict__ feat) {
  const int d = blockIdx.x;
  const int t = threadIdx.x;
  const int s0 = rowstart[d], s1 = rowstart[d + 1];
  const float ah = ahi[d];
  float m = -1e30f, l = 0.f, o = 0.f;
  for (int i = s0; i < s1; i += 4) {
    float av[4];
    u16 hv[4];
#pragma unroll
    for (int j = 0; j < 4; ++j) {
      if (i + j < s1) {
        int s = esrc[i + j];
        av[j] = alo[s];
        hv[j] = hbuf[(size_t)s * 64 + t];
      } else {
        av[j] = -1e38f;
        hv[j] = 0;
      }
    }
#pragma unroll
    for (int j = 0; j < 4; ++j) {
      float e = av[j] + ah;
      e = e > 0.f ? e : 0.2f * e;
      float mn = fmaxf(m, e);
      float sc = __expf(m - mn);
      float w = __expf(e - mn);
      l = l * sc + w;
      o = o * sc + w * bff(hv[j]);
      m = mn;
    }
  }
  float v = o / (l + 1e-16f) + bias[t];
  feat[(size_t)d * 64 + t] = v > 0.f ? v : __expf(v) - 1.f;
}

// ---------- segmented global mean pool (batch_idx sorted) ----------
__global__ __launch_bounds__(64) void pool_seg(
    const float* __restrict__ feat, const int* __restrict__ batch,
    float* __restrict__ gsum, float* __restrict__ gcnt) {
  const int b = blockIdx.x;
  const int t = threadIdx.x;
  int n0 = b * POOL_CHUNK;
  int n1 = n0 + POOL_CHUNK;
  if (n1 > N_NODES) n1 = N_NODES;
  if (n0 >= n1) return;
  int g = batch[n0];
  float acc = 0.f;
  int cnt = 0;
  for (int n = n0; n < n1; ++n) {
    int gn = batch[n];
    if (gn != g) {
      atomicAdd(&gsum[g * 64 + t], acc);
      if (t == 0) atomicAdd(&gcnt[g], (float)cnt);
      acc = 0.f; cnt = 0; g = gn;
    }
    acc += feat[(size_t)n * 64 + t];
    ++cnt;
  }
  atomicAdd(&gsum[g * 64 + t], acc);
  if (t == 0) atomicAdd(&gcnt[g], (float)cnt);
}

// ---------- fused MLP heads ----------
__global__ void heads(const float* __restrict__ gsum,
                      const float* __restrict__ gcnt,
                      const float* __restrict__ Wc1, const float* __restrict__ bc1,
                      const float* __restrict__ Wc2, const float* __restrict__ bc2,
                      const float* __restrict__ Wr1, const float* __restrict__ br1,
                      const float* __restrict__ Wr2, const float* __restrict__ br2,
                      float* __restrict__ out) {
  __shared__ float g[64];
  const int gi = blockIdx.x, j = threadIdx.x;
  float cnt = gcnt[gi];
  cnt = cnt < 1.f ? 1.f : cnt;
  g[j] = gsum[gi * 64 + j] / cnt;
  __syncthreads();
  float hc = bc1[j], hr = br1[j];
#pragma unroll 8
  for (int c = 0; c < 64; ++c) {
    float gv = g[c];
    hc += gv * Wc1[j * 64 + c];
    hr += gv * Wr1[j * 64 + c];
  }
  hc = fmaxf(hc, 0.f) * Wc2[j];
  hr = fmaxf(hr, 0.f) * Wr2[j];
#pragma unroll
  for (int off = 32; off; off >>= 1) {
    hc += __shfl_down(hc, off, 64);
    hr += __shfl_down(hr, off, 64);
  }
  if (j == 0) {
    out[gi] = hc + bc2[0];
    out[N_GRAPHS + gi] = hr + br2[0];
  }
}

extern "C" void kernel_launch(void* const* d_in, const int* in_sizes, int n_in,
                              void* d_out, int out_size, void* d_ws,
                              size_t ws_size, hipStream_t stream) {
  const float* x   = (const float*)d_in[0];
  const int* ei    = (const int*)d_in[1];
  const int* batch = (const int*)d_in[2];
  const float* W1  = (const float*)d_in[3];
  const float* as1 = (const float*)d_in[4];
  const float* ad1 = (const float*)d_in[5];
  const float* b1  = (const float*)d_in[6];
  const float* W2  = (const float*)d_in[7];
  const float* as2 = (const float*)d_in[8];
  const float* ad2 = (const float*)d_in[9];
  const float* b2  = (const float*)d_in[10];
  const float* W3  = (const float*)d_in[11];
  const float* as3 = (const float*)d_in[12];
  const float* ad3 = (const float*)d_in[13];
  const float* b3  = (const float*)d_in[14];
  const float* Wc1 = (const float*)d_in[15];
  const float* bc1 = (const float*)d_in[16];
  const float* Wc2 = (const float*)d_in[17];
  const float* bc2 = (const float*)d_in[18];
  const float* Wr1 = (const float*)d_in[19];
  const float* br1 = (const float*)d_in[20];
  const float* Wr2 = (const float*)d_in[21];
  const float* br2 = (const float*)d_in[22];
  float* out = (float*)d_out;

  // ---- workspace layout ----
  float* ws = (float*)d_ws;
  u16* h_buf = (u16*)ws;
  float* p = ws + (size_t)N_NODES * 128;
  u16* featb = (u16*)p;
  p += (size_t)N_NODES * 128;
  u16* xb = (u16*)p;
  p += (size_t)N_NODES * 64;
  u16* W1b = (u16*)p; p += 16384;
  u16* W2b = (u16*)p; p += 32768;
  u16* W3b = (u16*)p; p += 8192;
  float* feat3 = p;   p += (size_t)N_NODES * 64;
  float* alo   = p;   p += (size_t)N_NODES * 4;
  float* ahi   = p;   p += (size_t)N_NODES * 4;
  int* rowstart = (int*)p; p += (N_NODES + 4);
  int* esrc    = (int*)p;  p += EP_EDGES;
  float* gsum  = p;   p += N_GRAPHS * 64;
  float* gcnt  = p;
  int* deg  = (int*)alo;
  int* fill = (int*)ahi;
  int* bsum = (int*)gsum;
  int* boff = (int*)gsum + 256;

  // ---- CSR build ----
  hipMemsetAsync(deg, 0, (size_t)N_NODES * 4, stream);
  hipMemsetAsync(fill, 0, (size_t)N_NODES * 4, stream);
  const int eblk = (EP_EDGES + 255) / 256;
  k_hist<<<eblk, 256, 0, stream>>>(ei, deg);
  k_scan_local<<<NBLK_SCAN, 256, 0, stream>>>(deg, rowstart, bsum);
  k_scan_bsum<<<1, 256, 0, stream>>>(bsum, boff);
  k_scan_add<<<(N_NODES + 256) / 256, 256, 0, stream>>>(rowstart, boff);
  k_scatter<<<eblk, 256, 0, stream>>>(ei, rowstart, fill, esrc);

  // ---- input/weight bf16 conversion ----
  f2b<<<(N_NODES * 128 + 255) / 256, 256, 0, stream>>>(x, xb, N_NODES * 128);
  f2b<<<(32768 + 255) / 256, 256, 0, stream>>>(W1, W1b, 32768);
  f2b<<<(65536 + 255) / 256, 256, 0, stream>>>(W2, W2b, 65536);
  f2b<<<(16384 + 255) / 256, 256, 0, stream>>>(W3, W3b, 16384);

  const int MB = (N_NODES + 63) / 64;
  // ---- layer 1 ----
  gemm_bf16<<<dim3(4, MB), 256, 0, stream>>>(xb, W1b, h_buf, N_NODES, 256, 128);
  attn_scores<<<N_NODES, 256, 0, stream>>>(h_buf, as1, ad1, alo, ahi, 256, 4);
  agg_fused4<<<N_NODES, 128, 0, stream>>>(rowstart, esrc, h_buf, alo, ahi, b1,
                                          featb);
  // ---- layer 2 ----
  gemm_bf16<<<dim3(4, MB), 256, 0, stream>>>(featb, W2b, h_buf, N_NODES, 256, 256);
  attn_scores<<<N_NODES, 256, 0, stream>>>(h_buf, as2, ad2, alo, ahi, 256, 4);
  agg_fused4<<<N_NODES, 128, 0, stream>>>(rowstart, esrc, h_buf, alo, ahi, b2,
                                          featb);
  // ---- layer 3 ----
  gemm_bf16<<<dim3(1, MB), 256, 0, stream>>>(featb, W3b, h_buf, N_NODES, 64, 256);
  attn_scores<<<N_NODES, 64, 0, stream>>>(h_buf, as3, ad3, alo, ahi, 64, 1);
  agg_fused1<<<N_NODES, 64, 0, stream>>>(rowstart, esrc, h_buf, alo, ahi, b3,
                                         feat3);

  // ---- segmented mean pool + heads ----
  hipMemsetAsync(gsum, 0, (size_t)N_GRAPHS * 64 * 4, stream);
  hipMemsetAsync(gcnt, 0, (size_t)N_GRAPHS * 4, stream);
  pool_seg<<<N_GRAPHS, 64, 0, stream>>>(feat3, batch, gsum, gcnt);
  heads<<<N_GRAPHS, 64, 0, stream>>>(gsum, gcnt, Wc1, bc1, Wc2, bc2, Wr1, br1,
                                     Wr2, br2, out);
}

// Round 6
// 569.163 us; speedup vs baseline: 4.2340x; 1.0457x over previous
//
#include <hip/hip_runtime.h>

#define N_NODES 50000
#define N_EDGES 800000
#define EP_EDGES (N_EDGES + N_NODES)
#define N_GRAPHS 256
#define NBLK_SCAN ((N_NODES + 255) / 256)
#define POOL_CHUNK ((N_NODES + 255) / 256)

typedef unsigned short u16;
typedef __attribute__((ext_vector_type(8))) short s8v;    // 8 x bf16 (4 VGPRs)
typedef __attribute__((ext_vector_type(4))) float f4v;    // mfma accumulator

// ---------- bf16 helpers (RNE) ----------
__device__ __forceinline__ u16 fb(float f) {
  unsigned u = __float_as_uint(f);
  return (u16)((u + 0x7fffu + ((u >> 16) & 1u)) >> 16);
}
__device__ __forceinline__ float bff(u16 s) {
  return __uint_as_float(((unsigned)s) << 16);
}

__global__ void f2b(const float* __restrict__ in, u16* __restrict__ o, int n) {
  int i = blockIdx.x * 256 + threadIdx.x;
  if (i < n) o[i] = fb(in[i]);
}

// ---------- bf16 MFMA GEMM: C[M,Nout](bf16) = A[M,K](bf16) * W[Nout,K](bf16)^T
__global__ __launch_bounds__(256) void gemm_bf16(
    const u16* __restrict__ A, const u16* __restrict__ W,
    u16* __restrict__ C, int M, int Nout, int K) {
  __shared__ u16 As[64][40];
  __shared__ u16 Bs[64][40];
  const int t = threadIdx.x;
  const int m0 = blockIdx.y * 64, n0 = blockIdx.x * 64;
  const int r = t >> 2, c = t & 3;
  const int w = t >> 6, lane = t & 63;
  const int mi = (w & 1) * 32, ni = (w >> 1) * 32;
  const int quad = lane >> 4, fr = lane & 15;

  f4v c00{}, c01{}, c10{}, c11{};
  for (int k0 = 0; k0 < K; k0 += 32) {
    uint4 av = make_uint4(0, 0, 0, 0);
    int m = m0 + r;
    if (m < M) av = *(const uint4*)&A[(size_t)m * K + k0 + c * 8];
    uint4 bv = *(const uint4*)&W[(size_t)(n0 + r) * K + k0 + c * 8];
    __syncthreads();
    *(uint4*)&As[r][c * 8] = av;
    *(uint4*)&Bs[r][c * 8] = bv;
    __syncthreads();
    s8v a0 = *(const s8v*)&As[mi + fr][quad * 8];
    s8v a1 = *(const s8v*)&As[mi + 16 + fr][quad * 8];
    s8v b0 = *(const s8v*)&Bs[ni + fr][quad * 8];
    s8v b1 = *(const s8v*)&Bs[ni + 16 + fr][quad * 8];
    c00 = __builtin_amdgcn_mfma_f32_16x16x32_bf16(a0, b0, c00, 0, 0, 0);
    c01 = __builtin_amdgcn_mfma_f32_16x16x32_bf16(a0, b1, c01, 0, 0, 0);
    c10 = __builtin_amdgcn_mfma_f32_16x16x32_bf16(a1, b0, c10, 0, 0, 0);
    c11 = __builtin_amdgcn_mfma_f32_16x16x32_bf16(a1, b1, c11, 0, 0, 0);
  }
  const int col = n0 + ni + fr;
#pragma unroll
  for (int i = 0; i < 4; ++i) {
    int row = m0 + mi + quad * 4 + i;
    if (row < M) {
      C[(size_t)row * Nout + col] = fb(c00[i]);
      C[(size_t)row * Nout + col + 16] = fb(c01[i]);
    }
    int row2 = row + 16;
    if (row2 < M) {
      C[(size_t)row2 * Nout + col] = fb(c10[i]);
      C[(size_t)row2 * Nout + col + 16] = fb(c11[i]);
    }
  }
}

// ---------- CSR build ----------
__global__ void k_hist(const int* __restrict__ ei, int* __restrict__ deg) {
  int e = blockIdx.x * 256 + threadIdx.x;
  if (e >= EP_EDGES) return;
  int d = (e < N_EDGES) ? ei[N_EDGES + e] : e - N_EDGES;
  atomicAdd(&deg[d], 1);
}

__global__ void k_scan_local(const int* __restrict__ deg,
                             int* __restrict__ rowstart,
                             int* __restrict__ bsum) {
  __shared__ int sh[256];
  const int tid = threadIdx.x;
  const int i = blockIdx.x * 256 + tid;
  int v = (i < N_NODES) ? deg[i] : 0;
  sh[tid] = v;
  __syncthreads();
  for (int off = 1; off < 256; off <<= 1) {
    int add = (tid >= off) ? sh[tid - off] : 0;
    __syncthreads();
    sh[tid] += add;
    __syncthreads();
  }
  if (i < N_NODES) rowstart[i] = sh[tid] - v;
  if (tid == 255) bsum[blockIdx.x] = sh[255];
}

__global__ void k_scan_bsum(int* __restrict__ bsum, int* __restrict__ boff) {
  __shared__ int sh[256];
  const int tid = threadIdx.x;
  int v = (tid < NBLK_SCAN) ? bsum[tid] : 0;
  sh[tid] = v;
  __syncthreads();
  for (int off = 1; off < 256; off <<= 1) {
    int add = (tid >= off) ? sh[tid - off] : 0;
    __syncthreads();
    sh[tid] += add;
    __syncthreads();
  }
  boff[tid] = sh[tid] - v;
}

__global__ void k_scan_add(int* __restrict__ rowstart,
                           const int* __restrict__ boff) {
  int i = blockIdx.x * 256 + threadIdx.x;
  if (i < N_NODES) rowstart[i] += boff[i >> 8];
  if (i == N_NODES) rowstart[N_NODES] = EP_EDGES;
}

__global__ void k_scatter(const int* __restrict__ ei,
                          const int* __restrict__ rowstart,
                          int* __restrict__ fill, int* __restrict__ esrc) {
  int e = blockIdx.x * 256 + threadIdx.x;
  if (e >= EP_EDGES) return;
  int s, d;
  if (e < N_EDGES) { s = ei[e]; d = ei[N_EDGES + e]; }
  else             { s = d = e - N_EDGES; }
  int pos = rowstart[d] + atomicAdd(&fill[d], 1);
  esrc[pos] = s;
}

// ---------- per-node attention scores ----------
__global__ void attn_scores(const u16* __restrict__ h,
                            const float* __restrict__ a_src,
                            const float* __restrict__ a_dst,
                            float* __restrict__ alo, float* __restrict__ ahi,
                            int HC, int H) {
  const int n = blockIdx.x;
  const int t = threadIdx.x;
  float v = bff(h[(size_t)n * HC + t]);
  float s = v * a_src[t];
  float d = v * a_dst[t];
#pragma unroll
  for (int off = 32; off; off >>= 1) {
    s += __shfl_down(s, off, 64);
    d += __shfl_down(d, off, 64);
  }
  if ((t & 63) == 0) {
    int hd = t >> 6;
    alo[n * H + hd] = s;
    ahi[n * H + hd] = d;
  }
}

// ---------- aggregation v2, H=4: weights computed once, staged in LDS ----
// 128 thr/block (one dst); lane owns 2 channels; head = t>>5.
__global__ __launch_bounds__(128) void agg2_4(
    const int* __restrict__ rowstart, const int* __restrict__ esrc,
    const u16* __restrict__ hbuf, const float* __restrict__ alo,
    const float* __restrict__ ahi, const float* __restrict__ bias,
    u16* __restrict__ feat) {
  const int d = blockIdx.x;
  const int t = threadIdx.x;
  const int lane32 = t & 31;
  const int head = t >> 5;
  const int c = t * 2;
  const int s0 = rowstart[d], s1 = rowstart[d + 1];
  const float ah = ahi[d * 4 + head];

  // pass 1: per-head max (32 lanes stride the edge list)
  float mx = -1e30f;
  for (int j = s0 + lane32; j < s1; j += 32) {
    int s = esrc[j];
    float e = alo[s * 4 + head] + ah;
    e = e > 0.f ? e : 0.2f * e;
    mx = fmaxf(mx, e);
  }
#pragma unroll
  for (int off = 16; off; off >>= 1) mx = fmaxf(mx, __shfl_xor(mx, off, 64));
  // pass 2: denom
  float sm = 0.f;
  for (int j = s0 + lane32; j < s1; j += 32) {
    int s = esrc[j];
    float e = alo[s * 4 + head] + ah;
    e = e > 0.f ? e : 0.2f * e;
    sm += __expf(e - mx);
  }
#pragma unroll
  for (int off = 16; off; off >>= 1) sm += __shfl_xor(sm, off, 64);
  const float linv = 1.f / (sm + 1e-16f);

  // pass 3: chunked weighted gather-sum (pure FMA hot loop)
  __shared__ float wls[32][4];
  __shared__ int sld[32];
  float o0 = 0.f, o1 = 0.f;
  for (int base = s0; base < s1; base += 32) {
    int j = base + lane32;
    int s = d;
    float w = 0.f;
    if (j < s1) {
      s = esrc[j];
      float e = alo[s * 4 + head] + ah;
      e = e > 0.f ? e : 0.2f * e;
      w = __expf(e - mx) * linv;
    }
    __syncthreads();
    wls[lane32][head] = w;
    if (t < 32) sld[lane32] = s;  // lanes 0..31 are head 0, edge lane32
    __syncthreads();
    int cnt8 = (min(32, s1 - base) + 7) & ~7;
    for (int jj = 0; jj < cnt8; jj += 8) {
      float w2[8];
      int ss[8];
      unsigned hv[8];
#pragma unroll
      for (int q = 0; q < 8; ++q) {
        ss[q] = sld[jj + q];
        w2[q] = wls[jj + q][head];
      }
#pragma unroll
      for (int q = 0; q < 8; ++q)
        hv[q] = *(const unsigned*)&hbuf[(size_t)ss[q] * 256 + c];
#pragma unroll
      for (int q = 0; q < 8; ++q) {
        o0 += w2[q] * bff((u16)(hv[q] & 0xffffu));
        o1 += w2[q] * bff((u16)(hv[q] >> 16));
      }
    }
  }
  float v0 = o0 + bias[c], v1 = o1 + bias[c + 1];
  v0 = v0 > 0.f ? v0 : __expf(v0) - 1.f;
  v1 = v1 > 0.f ? v1 : __expf(v1) - 1.f;
  unsigned pv = (unsigned)fb(v0) | ((unsigned)fb(v1) << 16);
  *(unsigned*)&feat[(size_t)d * 256 + c] = pv;
}

// ---------- aggregation v2, H=1 (f32 out) ----------
__global__ __launch_bounds__(64) void agg2_1(
    const int* __restrict__ rowstart, const int* __restrict__ esrc,
    const u16* __restrict__ hbuf, const float* __restrict__ alo,
    const float* __restrict__ ahi, const float* __restrict__ bias,
    float* __restrict__ feat) {
  const int d = blockIdx.x;
  const int t = threadIdx.x;
  const int s0 = rowstart[d], s1 = rowstart[d + 1];
  const float ah = ahi[d];

  float mx = -1e30f;
  for (int j = s0 + t; j < s1; j += 64) {
    int s = esrc[j];
    float e = alo[s] + ah;
    e = e > 0.f ? e : 0.2f * e;
    mx = fmaxf(mx, e);
  }
#pragma unroll
  for (int off = 32; off; off >>= 1) mx = fmaxf(mx, __shfl_xor(mx, off, 64));
  float sm = 0.f;
  for (int j = s0 + t; j < s1; j += 64) {
    int s = esrc[j];
    float e = alo[s] + ah;
    e = e > 0.f ? e : 0.2f * e;
    sm += __expf(e - mx);
  }
#pragma unroll
  for (int off = 32; off; off >>= 1) sm += __shfl_xor(sm, off, 64);
  const float linv = 1.f / (sm + 1e-16f);

  __shared__ float wls[64];
  __shared__ int sld[64];
  float o = 0.f;
  for (int base = s0; base < s1; base += 64) {
    int j = base + t;
    int s = d;
    float w = 0.f;
    if (j < s1) {
      s = esrc[j];
      float e = alo[s] + ah;
      e = e > 0.f ? e : 0.2f * e;
      w = __expf(e - mx) * linv;
    }
    __syncthreads();
    wls[t] = w;
    sld[t] = s;
    __syncthreads();
    int cnt8 = (min(64, s1 - base) + 7) & ~7;
    for (int jj = 0; jj < cnt8; jj += 8) {
      float w2[8];
      int ss[8];
      u16 hv[8];
#pragma unroll
      for (int q = 0; q < 8; ++q) {
        ss[q] = sld[jj + q];
        w2[q] = wls[jj + q];
      }
#pragma unroll
      for (int q = 0; q < 8; ++q) hv[q] = hbuf[(size_t)ss[q] * 64 + t];
#pragma unroll
      for (int q = 0; q < 8; ++q) o += w2[q] * bff(hv[q]);
    }
  }
  float v = o + bias[t];
  feat[(size_t)d * 64 + t] = v > 0.f ? v : __expf(v) - 1.f;
}

// ---------- segmented global mean pool (batch_idx sorted) ----------
__global__ __launch_bounds__(64) void pool_seg(
    const float* __restrict__ feat, const int* __restrict__ batch,
    float* __restrict__ gsum, float* __restrict__ gcnt) {
  const int b = blockIdx.x;
  const int t = threadIdx.x;
  int n0 = b * POOL_CHUNK;
  int n1 = n0 + POOL_CHUNK;
  if (n1 > N_NODES) n1 = N_NODES;
  if (n0 >= n1) return;
  int g = batch[n0];
  float acc = 0.f;
  int cnt = 0;
  for (int n = n0; n < n1; ++n) {
    int gn = batch[n];
    if (gn != g) {
      atomicAdd(&gsum[g * 64 + t], acc);
      if (t == 0) atomicAdd(&gcnt[g], (float)cnt);
      acc = 0.f; cnt = 0; g = gn;
    }
    acc += feat[(size_t)n * 64 + t];
    ++cnt;
  }
  atomicAdd(&gsum[g * 64 + t], acc);
  if (t == 0) atomicAdd(&gcnt[g], (float)cnt);
}

// ---------- fused MLP heads ----------
__global__ void heads(const float* __restrict__ gsum,
                      const float* __restrict__ gcnt,
                      const float* __restrict__ Wc1, const float* __restrict__ bc1,
                      const float* __restrict__ Wc2, const float* __restrict__ bc2,
                      const float* __restrict__ Wr1, const float* __restrict__ br1,
                      const float* __restrict__ Wr2, const float* __restrict__ br2,
                      float* __restrict__ out) {
  __shared__ float g[64];
  const int gi = blockIdx.x, j = threadIdx.x;
  float cnt = gcnt[gi];
  cnt = cnt < 1.f ? 1.f : cnt;
  g[j] = gsum[gi * 64 + j] / cnt;
  __syncthreads();
  float hc = bc1[j], hr = br1[j];
#pragma unroll 8
  for (int c = 0; c < 64; ++c) {
    float gv = g[c];
    hc += gv * Wc1[j * 64 + c];
    hr += gv * Wr1[j * 64 + c];
  }
  hc = fmaxf(hc, 0.f) * Wc2[j];
  hr = fmaxf(hr, 0.f) * Wr2[j];
#pragma unroll
  for (int off = 32; off; off >>= 1) {
    hc += __shfl_down(hc, off, 64);
    hr += __shfl_down(hr, off, 64);
  }
  if (j == 0) {
    out[gi] = hc + bc2[0];
    out[N_GRAPHS + gi] = hr + br2[0];
  }
}

extern "C" void kernel_launch(void* const* d_in, const int* in_sizes, int n_in,
                              void* d_out, int out_size, void* d_ws,
                              size_t ws_size, hipStream_t stream) {
  const float* x   = (const float*)d_in[0];
  const int* ei    = (const int*)d_in[1];
  const int* batch = (const int*)d_in[2];
  const float* W1  = (const float*)d_in[3];
  const float* as1 = (const float*)d_in[4];
  const float* ad1 = (const float*)d_in[5];
  const float* b1  = (const float*)d_in[6];
  const float* W2  = (const float*)d_in[7];
  const float* as2 = (const float*)d_in[8];
  const float* ad2 = (const float*)d_in[9];
  const float* b2  = (const float*)d_in[10];
  const float* W3  = (const float*)d_in[11];
  const float* as3 = (const float*)d_in[12];
  const float* ad3 = (const float*)d_in[13];
  const float* b3  = (const float*)d_in[14];
  const float* Wc1 = (const float*)d_in[15];
  const float* bc1 = (const float*)d_in[16];
  const float* Wc2 = (const float*)d_in[17];
  const float* bc2 = (const float*)d_in[18];
  const float* Wr1 = (const float*)d_in[19];
  const float* br1 = (const float*)d_in[20];
  const float* Wr2 = (const float*)d_in[21];
  const float* br2 = (const float*)d_in[22];
  float* out = (float*)d_out;

  // ---- workspace layout ----
  float* ws = (float*)d_ws;
  u16* h_buf = (u16*)ws;
  float* p = ws + (size_t)N_NODES * 128;
  u16* featb = (u16*)p;
  p += (size_t)N_NODES * 128;
  u16* xb = (u16*)p;
  p += (size_t)N_NODES * 64;
  u16* W1b = (u16*)p; p += 16384;
  u16* W2b = (u16*)p; p += 32768;
  u16* W3b = (u16*)p; p += 8192;
  float* feat3 = p;   p += (size_t)N_NODES * 64;
  float* alo   = p;   p += (size_t)N_NODES * 4;
  float* ahi   = p;   p += (size_t)N_NODES * 4;
  int* rowstart = (int*)p; p += (N_NODES + 4);
  int* esrc    = (int*)p;  p += EP_EDGES;
  float* gsum  = p;   p += N_GRAPHS * 64;
  float* gcnt  = p;
  int* deg  = (int*)alo;
  int* fill = (int*)ahi;
  int* bsum = (int*)gsum;
  int* boff = (int*)gsum + 256;

  // ---- CSR build ----
  hipMemsetAsync(deg, 0, (size_t)N_NODES * 4, stream);
  hipMemsetAsync(fill, 0, (size_t)N_NODES * 4, stream);
  const int eblk = (EP_EDGES + 255) / 256;
  k_hist<<<eblk, 256, 0, stream>>>(ei, deg);
  k_scan_local<<<NBLK_SCAN, 256, 0, stream>>>(deg, rowstart, bsum);
  k_scan_bsum<<<1, 256, 0, stream>>>(bsum, boff);
  k_scan_add<<<(N_NODES + 256) / 256, 256, 0, stream>>>(rowstart, boff);
  k_scatter<<<eblk, 256, 0, stream>>>(ei, rowstart, fill, esrc);

  // ---- input/weight bf16 conversion ----
  f2b<<<(N_NODES * 128 + 255) / 256, 256, 0, stream>>>(x, xb, N_NODES * 128);
  f2b<<<(32768 + 255) / 256, 256, 0, stream>>>(W1, W1b, 32768);
  f2b<<<(65536 + 255) / 256, 256, 0, stream>>>(W2, W2b, 65536);
  f2b<<<(16384 + 255) / 256, 256, 0, stream>>>(W3, W3b, 16384);

  const int MB = (N_NODES + 63) / 64;
  // ---- layer 1 ----
  gemm_bf16<<<dim3(4, MB), 256, 0, stream>>>(xb, W1b, h_buf, N_NODES, 256, 128);
  attn_scores<<<N_NODES, 256, 0, stream>>>(h_buf, as1, ad1, alo, ahi, 256, 4);
  agg2_4<<<N_NODES, 128, 0, stream>>>(rowstart, esrc, h_buf, alo, ahi, b1,
                                      featb);
  // ---- layer 2 ----
  gemm_bf16<<<dim3(4, MB), 256, 0, stream>>>(featb, W2b, h_buf, N_NODES, 256, 256);
  attn_scores<<<N_NODES, 256, 0, stream>>>(h_buf, as2, ad2, alo, ahi, 256, 4);
  agg2_4<<<N_NODES, 128, 0, stream>>>(rowstart, esrc, h_buf, alo, ahi, b2,
                                      featb);
  // ---- layer 3 ----
  gemm_bf16<<<dim3(1, MB), 256, 0, stream>>>(featb, W3b, h_buf, N_NODES, 64, 256);
  attn_scores<<<N_NODES, 64, 0, stream>>>(h_buf, as3, ad3, alo, ahi, 64, 1);
  agg2_1<<<N_NODES, 64, 0, stream>>>(rowstart, esrc, h_buf, alo, ahi, b3,
                                     feat3);

  // ---- segmented mean pool + heads ----
  hipMemsetAsync(gsum, 0, (size_t)N_GRAPHS * 64 * 4, stream);
  hipMemsetAsync(gcnt, 0, (size_t)N_GRAPHS * 4, stream);
  pool_seg<<<N_GRAPHS, 64, 0, stream>>>(feat3, batch, gsum, gcnt);
  heads<<<N_GRAPHS, 64, 0, stream>>>(gsum, gcnt, Wc1, bc1, Wc2, bc2, Wr1, br1,
                                     Wr2, br2, out);
}